// Round 1
// baseline (886.637 us; speedup 1.0000x reference)
//
#include <hip/hip_runtime.h>

#define NB 17340      // 15*34*34
#define TOPK1 3000
#define ROUNDS1 300
#define TOPK2 300
#define ROUNDS2 5

__constant__ float c_AW[15] = {9.232984, 16.0, 27.712813, 18.465969, 32.0, 55.425626,
                               36.931937, 64.0, 110.851252, 73.863875, 128.0, 221.702503,
                               147.72775, 256.0, 443.405007};
__constant__ float c_AH[15] = {27.72668, 16.0, 9.237604, 55.453359, 32.0, 18.475209,
                               110.906719, 64.0, 36.950417, 221.813438, 128.0, 73.900834,
                               443.626876, 256.0, 147.801669};

__device__ __forceinline__ unsigned mapf(float f) {
  unsigned u = __float_as_uint(f);
  return (u & 0x80000000u) ? ~u : (u | 0x80000000u);
}
__device__ __forceinline__ float unmapf(unsigned m) {
  unsigned u = (m & 0x80000000u) ? (m & 0x7FFFFFFFu) : ~m;
  return __uint_as_float(u);
}
__device__ __forceinline__ unsigned long long shflxor64(unsigned long long v, int m) {
  unsigned lo = (unsigned)__shfl_xor((int)(unsigned)v, m);
  unsigned hi = (unsigned)__shfl_xor((int)(unsigned)(v >> 32), m);
  return ((unsigned long long)hi << 32) | lo;
}
__device__ __forceinline__ float clipc(float v) {
  return fminf(fmaxf(v, 0.0f), 269.0f);
}

// ---------------- Kernel 1: RPN decode + keep filter ----------------
__global__ void k_decode(const float* __restrict__ cls, const float* __restrict__ pred,
                         float* __restrict__ boxes, float* __restrict__ scores) {
  int i = blockIdx.x * 256 + threadIdx.x;
  if (i >= NB) return;
  int a = i / 1156;
  int rem = i - a * 1156;
  int y = rem / 34;
  int x = rem - y * 34;
  float fg = cls[(15 + a) * 1156 + rem];
  const float* p = pred + a * 4 * 1156 + rem;
  float t0 = p[0]    * (float)0.12677  + (float)0.000437;
  float t1 = p[1156] * (float)0.095741 + (float)0.002586;
  float t2 = p[2312] * (float)0.3173   + (float)-0.123953;
  float t3 = p[3468] * (float)0.281042 + (float)-0.081469;
  float aw = c_AW[a], ah = c_AH[a];
  float cx = t0 * aw + (float)x * 8.0f;
  float cy = t1 * ah + (float)y * 8.0f;
  float bw = expf(t2) * aw;
  float bh = expf(t3) * ah;
  float x1 = clipc(cx - 0.5f * (bw - 1.0f));
  float y1 = clipc(cy - 0.5f * (bh - 1.0f));
  float x2 = clipc(cx + 0.5f * (bw - 1.0f));
  float y2 = clipc(cy + 0.5f * (bh - 1.0f));
  boxes[i * 4 + 0] = x1;
  boxes[i * 4 + 1] = y1;
  boxes[i * 4 + 2] = x2;
  boxes[i * 4 + 3] = y2;
  float w2 = x2 - x1 + 1.0f, h2 = y2 - y1 + 1.0f;
  bool keep = (fg >= 0.2f) && ((w2 >= (float)6.16056) || (h2 >= (float)6.16056));
  scores[i] = keep ? fg : -1.0f;
}

// ---------------- Kernel 2: exact top-3000 (radix select) + NMS 300 ----------------
__global__ __launch_bounds__(1024) void k_nms1(const float* __restrict__ boxes,
                                               const float* __restrict__ scores,
                                               float* __restrict__ dout,
                                               float* __restrict__ rois_xy,
                                               float* __restrict__ validf) {
  const int t = threadIdx.x;
  __shared__ int s_wsum[16];
  __shared__ unsigned long long wred[16];
  __shared__ int s_take;
  __shared__ int s_rem;
  __shared__ unsigned long long s_pref;
  __shared__ int s_cnt;
  __shared__ int s_idx[TOPK1];
  __shared__ float s_box[5];

  // key = (monotone score bits << 15) | (32767 - idx) : order == (score desc, idx asc)
  unsigned long long key[17];
#pragma unroll
  for (int j = 0; j < 17; ++j) {
    int i = t + j * 1024;
    if (i < NB)
      key[j] = ((unsigned long long)mapf(scores[i]) << 15) | (unsigned)(32767 - i);
    else
      key[j] = 0ull;
  }
  unsigned act = 0x1FFFFu;
  if (t == 0) { s_rem = TOPK1; s_pref = 0ull; }
  __syncthreads();
  for (int b = 46; b >= 0; --b) {
    int c = 0;
#pragma unroll
    for (int j = 0; j < 17; ++j)
      if ((act >> j) & 1u) c += (int)((key[j] >> b) & 1ull);
    for (int off = 32; off > 0; off >>= 1) c += __shfl_xor(c, off);
    if ((t & 63) == 0) s_wsum[t >> 6] = c;
    __syncthreads();
    if (t == 0) {
      int tot = 0;
      for (int w = 0; w < 16; ++w) tot += s_wsum[w];
      if (tot >= s_rem) { s_take = 1; s_pref |= (1ull << b); }
      else { s_take = 0; s_rem -= tot; }
    }
    __syncthreads();
    int take = s_take;
#pragma unroll
    for (int j = 0; j < 17; ++j)
      if ((act >> j) & 1u)
        if ((int)((key[j] >> b) & 1ull) != take) act &= ~(1u << j);
  }
  unsigned long long cutoff = s_pref;  // the exact 3000th-largest key (keys unique)
  if (t == 0) s_cnt = 0;
  __syncthreads();
#pragma unroll
  for (int j = 0; j < 17; ++j) {
    if (key[j] >= cutoff) {
      int p = atomicAdd(&s_cnt, 1);
      s_idx[p] = t + j * 1024;
    }
  }
  __syncthreads();

  // load NMS entries (exactly 3000 compacted; permutation irrelevant: argmax uses full key)
  float ex1[3], ey1[3], ex2[3], ey2[3], esc[3], ear[3];
  int eidx[3];
  bool ealive[3];
#pragma unroll
  for (int e = 0; e < 3; ++e) {
    int pos = t + e * 1024;
    ealive[e] = false; eidx[e] = -1;
    ex1[e] = ey1[e] = ex2[e] = ey2[e] = ear[e] = 0.f; esc[e] = -2.f;
    if (pos < TOPK1) {
      int idx = s_idx[pos];
      ex1[e] = boxes[idx * 4 + 0]; ey1[e] = boxes[idx * 4 + 1];
      ex2[e] = boxes[idx * 4 + 2]; ey2[e] = boxes[idx * 4 + 3];
      esc[e] = scores[idx];
      ear[e] = (ex2[e] - ex1[e] + 1.0f) * (ey2[e] - ey1[e] + 1.0f);
      eidx[e] = idx; ealive[e] = true;
    }
  }
  int r = 0;
  for (; r < ROUNDS1; ++r) {
    unsigned long long best = 0ull;
#pragma unroll
    for (int e = 0; e < 3; ++e)
      if (ealive[e]) {
        unsigned long long k = ((unsigned long long)mapf(esc[e]) << 15) | (unsigned)(32767 - eidx[e]);
        if (k > best) best = k;
      }
    for (int off = 32; off > 0; off >>= 1) {
      unsigned long long o = shflxor64(best, off);
      if (o > best) best = o;
    }
    if ((t & 63) == 0) wred[t >> 6] = best;
    __syncthreads();
    unsigned long long bk = wred[0];
    for (int w = 1; w < 16; ++w) if (wred[w] > bk) bk = wred[w];
    float bsc = unmapf((unsigned)(bk >> 15));
    bool bvalid = (bsc > 0.0f);   // false also when bk==0 (unmap -> NaN)
    int widx = 32767 - (int)(bk & 32767ull);
#pragma unroll
    for (int e = 0; e < 3; ++e) {
      if (ealive[e] && eidx[e] == widx) {   // unique winner thread
        s_box[0] = ex1[e]; s_box[1] = ey1[e]; s_box[2] = ex2[e]; s_box[3] = ey2[e]; s_box[4] = ear[e];
        if (bvalid) {
          dout[30 + r * 5 + 0] = 0.0f;
          dout[30 + r * 5 + 1] = ex1[e];
          dout[30 + r * 5 + 2] = ey1[e];
          dout[30 + r * 5 + 3] = ex2[e];
          dout[30 + r * 5 + 4] = ey2[e];
          dout[1530 + r] = esc[e];
          rois_xy[r * 4 + 0] = ex1[e]; rois_xy[r * 4 + 1] = ey1[e];
          rois_xy[r * 4 + 2] = ex2[e]; rois_xy[r * 4 + 3] = ey2[e];
          validf[r] = 1.0f;
        }
      }
    }
    __syncthreads();
    if (!bvalid) break;   // all remaining reference rounds are invalid -> zero rows
    float bx1 = s_box[0], by1 = s_box[1], bx2 = s_box[2], by2 = s_box[3], ba = s_box[4];
#pragma unroll
    for (int e = 0; e < 3; ++e)
      if (ealive[e]) {
        float iw = fmaxf(fminf(ex2[e], bx2) - fmaxf(ex1[e], bx1) + 1.0f, 0.0f);
        float ih = fmaxf(fminf(ey2[e], by2) - fmaxf(ey1[e], by1) + 1.0f, 0.0f);
        float inter = iw * ih;
        float iou = inter / (ear[e] + ba - inter);
        if (iou > 0.7f) ealive[e] = false;   // winner suppresses itself (iou==1)
      }
  }
  if (r < ROUNDS1) {  // zero-fill invalid tail rows
    for (int z = 30 + r * 5 + t; z < 1530; z += 1024) dout[z] = 0.f;
    for (int z = 1530 + r + t; z < 1830; z += 1024) dout[z] = 0.f;
    for (int z = r * 4 + t; z < 1200; z += 1024) rois_xy[z] = 0.f;
    for (int z = r + t; z < 300; z += 1024) validf[z] = 0.f;
  }
}

// ---------------- Kernel 3: PSROI pooling (block per ROI) ----------------
__global__ __launch_bounds__(256) void k_psroi(const float* __restrict__ ft,
                                               const float* __restrict__ rois_xy,
                                               float* __restrict__ pooled) {
  int r = blockIdx.x;
  float r0 = rois_xy[r * 4 + 0], r1 = rois_xy[r * 4 + 1];
  float r2 = rois_xy[r * 4 + 2], r3 = rois_xy[r * 4 + 3];
  float sw = r0 * 0.125f;
  float sh = r1 * 0.125f;
  float ew = (r2 + 1.0f) * 0.125f;
  float eh = (r3 + 1.0f) * 0.125f;
  float rh = fmaxf(eh - sh, 0.1f);
  float rw = fmaxf(ew - sw, 0.1f);
  float bh = rh / 7.0f;
  float bwd = rw / 7.0f;
  for (int o = threadIdx.x; o < 490; o += 256) {
    // channel = c*49 + p*7 + q == o  (pooled flat index == input channel index)
    int p = (o % 49) / 7;
    int q = o % 7;
    const float* base = ft + o * 1156;
    float acc = 0.f;
#pragma unroll
    for (int sy = 0; sy < 4; ++sy) {
      float ys = sh + (float)p * bh + ((float)sy + 0.5f) * (bh * 0.25f);
      float y0f = floorf(ys);
      float dy = ys - y0f;
      int y0 = (int)y0f;
      float wy0 = (1.0f - dy) * ((y0 >= 0 && y0 < 34) ? 1.f : 0.f);
      float wy1 = dy * ((y0 + 1 >= 0 && y0 + 1 < 34) ? 1.f : 0.f);
      int yc0 = min(max(y0, 0), 33), yc1 = min(max(y0 + 1, 0), 33);
#pragma unroll
      for (int sx = 0; sx < 4; ++sx) {
        float xs = sw + (float)q * bwd + ((float)sx + 0.5f) * (bwd * 0.25f);
        float x0f = floorf(xs);
        float dx = xs - x0f;
        int x0 = (int)x0f;
        float wx0 = (1.0f - dx) * ((x0 >= 0 && x0 < 34) ? 1.f : 0.f);
        float wx1 = dx * ((x0 + 1 >= 0 && x0 + 1 < 34) ? 1.f : 0.f);
        int xc0 = min(max(x0, 0), 33), xc1 = min(max(x0 + 1, 0), 33);
        float v00 = base[yc0 * 34 + xc0], v01 = base[yc0 * 34 + xc1];
        float v10 = base[yc1 * 34 + xc0], v11 = base[yc1 * 34 + xc1];
        acc += wy0 * wx0 * v00 + wy0 * wx1 * v01 + wy1 * wx0 * v10 + wy1 * wx1 * v11;
      }
    }
    pooled[r * 490 + o] = acc * (1.0f / 16.0f);
  }
}

// ---------------- Kernel 4: FC1 (490 -> 2048) + ReLU ----------------
// grid (8,19): 256 outs per block.x, 16 rois per block.y; pooled tile in LDS.
__global__ __launch_bounds__(256) void k_fc1(const float* __restrict__ pooled,
                                             const float* __restrict__ Wi,
                                             const float* __restrict__ bi,
                                             float* __restrict__ feat) {
  __shared__ float pt[490][20];   // [k][roi], padded to 20 (16B-aligned rows, spread write banks)
  int t = threadIdx.x;
  int o = blockIdx.x * 256 + t;
  int r0 = blockIdx.y * 16;
  for (int idx = t; idx < 16 * 490; idx += 256) {
    int rr = idx / 490, kk = idx - rr * 490;
    pt[kk][rr] = (r0 + rr < 300) ? pooled[(r0 + rr) * 490 + kk] : 0.f;
  }
  __syncthreads();
  float acc[16];
#pragma unroll
  for (int e = 0; e < 16; ++e) acc[e] = 0.f;
  const float* wrow = Wi + o * 490;
  for (int k = 0; k < 490; ++k) {
    float wv = wrow[k];
    const float4* p4 = (const float4*)(&pt[k][0]);
    float4 a0 = p4[0], a1 = p4[1], a2 = p4[2], a3 = p4[3];
    acc[0] += wv * a0.x;  acc[1] += wv * a0.y;  acc[2] += wv * a0.z;  acc[3] += wv * a0.w;
    acc[4] += wv * a1.x;  acc[5] += wv * a1.y;  acc[6] += wv * a1.z;  acc[7] += wv * a1.w;
    acc[8] += wv * a2.x;  acc[9] += wv * a2.y;  acc[10] += wv * a2.z; acc[11] += wv * a2.w;
    acc[12] += wv * a3.x; acc[13] += wv * a3.y; acc[14] += wv * a3.z; acc[15] += wv * a3.w;
  }
  float bias = bi[o];
#pragma unroll
  for (int e = 0; e < 16; ++e) {
    int rr = r0 + e;
    if (rr < 300) feat[rr * 2048 + o] = fmaxf(acc[e] + bias, 0.f);
  }
}

// ---------------- Kernel 5: FC2 heads + softmax + per-class decode ----------------
__global__ __launch_bounds__(256) void k_fc2d(const float* __restrict__ feat,
                                              const float* __restrict__ Wc,
                                              const float* __restrict__ bc,
                                              const float* __restrict__ Wb,
                                              const float* __restrict__ bb,
                                              const float* __restrict__ rois_xy,
                                              const float* __restrict__ validf,
                                              float* __restrict__ db2,
                                              float* __restrict__ msc2) {
  int r = blockIdx.x;
  int t = threadIdx.x;
  int oid = t & 31, part = t >> 5;   // 8 parts x 32 slots (20 used)
  __shared__ float red[8][33];
  __shared__ float s_logit[20];
  __shared__ float s_probs[4];
  float partial = 0.f;
  if (oid < 20) {
    const float* frow = feat + r * 2048 + part * 256;
    const float* wrow = (oid < 4 ? Wc + oid * 2048 : Wb + (oid - 4) * 2048) + part * 256;
    for (int k = 0; k < 256; ++k) partial += frow[k] * wrow[k];
  }
  red[part][oid] = partial;
  __syncthreads();
  if (t < 20) {
    float s = 0.f;
    for (int pz = 0; pz < 8; ++pz) s += red[pz][t];
    s_logit[t] = s + (t < 4 ? bc[t] : bb[t - 4]);
  }
  __syncthreads();
  if (t == 0) {
    float m = fmaxf(fmaxf(s_logit[0], s_logit[1]), fmaxf(s_logit[2], s_logit[3]));
    float e0 = expf(s_logit[0] - m), e1 = expf(s_logit[1] - m);
    float e2 = expf(s_logit[2] - m), e3 = expf(s_logit[3] - m);
    float ssum = e0 + e1 + e2 + e3;
    s_probs[0] = e0 / ssum; s_probs[1] = e1 / ssum;
    s_probs[2] = e2 / ssum; s_probs[3] = e3 / ssum;
  }
  __syncthreads();
  if (t < 3) {
    int c = t + 1;
    float x1 = rois_xy[r * 4 + 0], y1 = rois_xy[r * 4 + 1];
    float x2 = rois_xy[r * 4 + 2], y2 = rois_xy[r * 4 + 3];
    float rwv = x2 - x1 + 1.0f, rhv = y2 - y1 + 1.0f;
    float rcx = x1 + 0.5f * (rwv - 1.0f), rcy = y1 + 0.5f * (rhv - 1.0f);
    // bpred col j == s_logit[4+j]; tc = bpred[4c .. 4c+3] * RCNN_STD
    float t0 = s_logit[4 + 4 * c + 0] * 0.1f;
    float t1 = s_logit[4 + 4 * c + 1] * 0.1f;
    float t2 = s_logit[4 + 4 * c + 2] * 0.2f;
    float t3 = s_logit[4 + 4 * c + 3] * 0.2f;
    float cx = t0 * rwv + rcx, cy = t1 * rhv + rcy;
    float bw = expf(t2) * rwv, bh = expf(t3) * rhv;
    float dx1 = clipc(cx - 0.5f * (bw - 1.0f));
    float dy1 = clipc(cy - 0.5f * (bh - 1.0f));
    float dx2 = clipc(cx + 0.5f * (bw - 1.0f));
    float dy2 = clipc(cy + 0.5f * (bh - 1.0f));
    float dw = dx2 - dx1 + 1.0f, dh = dy2 - dy1 + 1.0f;
    float sc = s_probs[c];
    bool objok = (1.0f - s_probs[0]) >= 0.1f;
    bool valid = validf[r] > 0.5f;
    bool kf = valid && objok && (sc >= 0.1f) && ((dw >= (float)8.8008) || (dh >= (float)8.8008));
    int i2 = (c - 1) * 300 + r;
    db2[i2 * 4 + 0] = dx1; db2[i2 * 4 + 1] = dy1;
    db2[i2 * 4 + 2] = dx2; db2[i2 * 4 + 3] = dy2;
    msc2[i2] = kf ? sc : -1.0f;
  }
}

// ---------------- Kernel 6: exact top-300 of 900 + NMS 5 -> bboxes ----------------
__global__ __launch_bounds__(256) void k_nms2(const float* __restrict__ db2,
                                              const float* __restrict__ msc2,
                                              float* __restrict__ dout) {
  const int t = threadIdx.x;
  __shared__ int s_wsum[4];
  __shared__ unsigned long long wred[4];
  __shared__ int s_take;
  __shared__ int s_rem;
  __shared__ unsigned long long s_pref;
  __shared__ int s_cnt;
  __shared__ int s_idx[TOPK2];
  __shared__ float s_box[5];

  unsigned long long key[4];
#pragma unroll
  for (int j = 0; j < 4; ++j) {
    int i = t + j * 256;
    key[j] = (i < 900) ? (((unsigned long long)mapf(msc2[i]) << 10) | (unsigned)(1023 - i)) : 0ull;
  }
  unsigned act = 0xFu;
  if (t == 0) { s_rem = TOPK2; s_pref = 0ull; }
  __syncthreads();
  for (int b = 41; b >= 0; --b) {
    int c = 0;
#pragma unroll
    for (int j = 0; j < 4; ++j)
      if ((act >> j) & 1u) c += (int)((key[j] >> b) & 1ull);
    for (int off = 32; off > 0; off >>= 1) c += __shfl_xor(c, off);
    if ((t & 63) == 0) s_wsum[t >> 6] = c;
    __syncthreads();
    if (t == 0) {
      int tot = s_wsum[0] + s_wsum[1] + s_wsum[2] + s_wsum[3];
      if (tot >= s_rem) { s_take = 1; s_pref |= (1ull << b); }
      else { s_take = 0; s_rem -= tot; }
    }
    __syncthreads();
    int take = s_take;
#pragma unroll
    for (int j = 0; j < 4; ++j)
      if ((act >> j) & 1u)
        if ((int)((key[j] >> b) & 1ull) != take) act &= ~(1u << j);
  }
  unsigned long long cutoff = s_pref;
  if (t == 0) s_cnt = 0;
  __syncthreads();
#pragma unroll
  for (int j = 0; j < 4; ++j)
    if (key[j] >= cutoff) { int p = atomicAdd(&s_cnt, 1); s_idx[p] = t + j * 256; }
  __syncthreads();

  float ex1[2], ey1[2], ex2[2], ey2[2], esc[2], ear[2], elab[2];
  int eidx[2];
  bool ealive[2];
#pragma unroll
  for (int e = 0; e < 2; ++e) {
    int pos = t + e * 256;
    ealive[e] = false; eidx[e] = -1;
    ex1[e] = ey1[e] = ex2[e] = ey2[e] = ear[e] = elab[e] = 0.f; esc[e] = -2.f;
    if (pos < TOPK2) {
      int idx = s_idx[pos];
      ex1[e] = db2[idx * 4 + 0]; ey1[e] = db2[idx * 4 + 1];
      ex2[e] = db2[idx * 4 + 2]; ey2[e] = db2[idx * 4 + 3];
      esc[e] = msc2[idx];
      ear[e] = (ex2[e] - ex1[e] + 1.0f) * (ey2[e] - ey1[e] + 1.0f);
      elab[e] = (float)(idx / 300 + 1);
      eidx[e] = idx; ealive[e] = true;
    }
  }
  int r = 0;
  for (; r < ROUNDS2; ++r) {
    unsigned long long best = 0ull;
#pragma unroll
    for (int e = 0; e < 2; ++e)
      if (ealive[e]) {
        unsigned long long k = ((unsigned long long)mapf(esc[e]) << 10) | (unsigned)(1023 - eidx[e]);
        if (k > best) best = k;
      }
    for (int off = 32; off > 0; off >>= 1) {
      unsigned long long o = shflxor64(best, off);
      if (o > best) best = o;
    }
    if ((t & 63) == 0) wred[t >> 6] = best;
    __syncthreads();
    unsigned long long bk = wred[0];
    for (int w = 1; w < 4; ++w) if (wred[w] > bk) bk = wred[w];
    float bsc = unmapf((unsigned)(bk >> 10));
    bool bvalid = (bsc > 0.0f);
    int widx = 1023 - (int)(bk & 1023ull);
#pragma unroll
    for (int e = 0; e < 2; ++e) {
      if (ealive[e] && eidx[e] == widx) {
        s_box[0] = ex1[e]; s_box[1] = ey1[e]; s_box[2] = ex2[e]; s_box[3] = ey2[e]; s_box[4] = ear[e];
        if (bvalid) {
          dout[r * 6 + 0] = ex1[e]; dout[r * 6 + 1] = ey1[e];
          dout[r * 6 + 2] = ex2[e]; dout[r * 6 + 3] = ey2[e];
          dout[r * 6 + 4] = esc[e]; dout[r * 6 + 5] = elab[e];
        }
      }
    }
    __syncthreads();
    if (!bvalid) break;
    float bx1 = s_box[0], by1 = s_box[1], bx2 = s_box[2], by2 = s_box[3], ba = s_box[4];
#pragma unroll
    for (int e = 0; e < 2; ++e)
      if (ealive[e]) {
        float iw = fmaxf(fminf(ex2[e], bx2) - fmaxf(ex1[e], bx1) + 1.0f, 0.0f);
        float ih = fmaxf(fminf(ey2[e], by2) - fmaxf(ey1[e], by1) + 1.0f, 0.0f);
        float inter = iw * ih;
        float iou = inter / (ear[e] + ba - inter);
        if (iou > 0.5f) ealive[e] = false;
      }
  }
  if (r < ROUNDS2) {
    for (int z = r * 6 + t; z < 30; z += 256) dout[z] = 0.f;
  }
}

extern "C" void kernel_launch(void* const* d_in, const int* in_sizes, int n_in,
                              void* d_out, int out_size, void* d_ws, size_t ws_size,
                              hipStream_t stream) {
  const float* cls  = (const float*)d_in[0];
  const float* pred = (const float*)d_in[1];
  const float* ft   = (const float*)d_in[2];
  const float* Wi   = (const float*)d_in[3];
  const float* bi   = (const float*)d_in[4];
  const float* Wc   = (const float*)d_in[5];
  const float* bc   = (const float*)d_in[6];
  const float* Wb   = (const float*)d_in[7];
  const float* bb   = (const float*)d_in[8];
  float* out = (float*)d_out;
  float* w = (float*)d_ws;
  float* boxes   = w;              // 17340*4 = 69360
  float* scores  = w + 69360;      // 17340          -> 86700
  float* rois_xy = w + 86700;      // 300*4 = 1200   -> 87900
  float* validf  = w + 87900;      // 300            -> 88200
  float* pooled  = w + 88200;      // 300*490=147000 -> 235200
  float* feat    = w + 235200;     // 300*2048=614400-> 849600
  float* db2     = w + 849600;     // 900*4 = 3600   -> 853200
  float* msc2    = w + 853200;     // 900            -> 854100 floats (~3.42 MB)

  k_decode<<<68, 256, 0, stream>>>(cls, pred, boxes, scores);
  k_nms1<<<1, 1024, 0, stream>>>(boxes, scores, out, rois_xy, validf);
  k_psroi<<<300, 256, 0, stream>>>(ft, rois_xy, pooled);
  k_fc1<<<dim3(8, 19), 256, 0, stream>>>(pooled, Wi, bi, feat);
  k_fc2d<<<300, 256, 0, stream>>>(feat, Wc, bc, Wb, bb, rois_xy, validf, db2, msc2);
  k_nms2<<<1, 256, 0, stream>>>(db2, msc2, out);
}

// Round 2
// 432.479 us; speedup vs baseline: 2.0501x; 2.0501x over previous
//
#include <hip/hip_runtime.h>

#define NB 17340      // 15*34*34
#define TOPK1 3000
#define TOPK2 300
#define ROUNDS2 5

__constant__ float c_AW[15] = {9.232984, 16.0, 27.712813, 18.465969, 32.0, 55.425626,
                               36.931937, 64.0, 110.851252, 73.863875, 128.0, 221.702503,
                               147.72775, 256.0, 443.405007};
__constant__ float c_AH[15] = {27.72668, 16.0, 9.237604, 55.453359, 32.0, 18.475209,
                               110.906719, 64.0, 36.950417, 221.813438, 128.0, 73.900834,
                               443.626876, 256.0, 147.801669};

__device__ __forceinline__ unsigned mapf(float f) {
  unsigned u = __float_as_uint(f);
  return (u & 0x80000000u) ? ~u : (u | 0x80000000u);
}
__device__ __forceinline__ float unmapf(unsigned m) {
  unsigned u = (m & 0x80000000u) ? (m & 0x7FFFFFFFu) : ~m;
  return __uint_as_float(u);
}
__device__ __forceinline__ unsigned long long shflxor64(unsigned long long v, int m) {
  unsigned lo = (unsigned)__shfl_xor((int)(unsigned)v, m);
  unsigned hi = (unsigned)__shfl_xor((int)(unsigned)(v >> 32), m);
  return ((unsigned long long)hi << 32) | lo;
}
__device__ __forceinline__ float clipc(float v) {
  return fminf(fmaxf(v, 0.0f), 269.0f);
}

// ---------------- Kernel 1: RPN decode + keep filter ----------------
__global__ void k_decode(const float* __restrict__ cls, const float* __restrict__ pred,
                         float* __restrict__ boxes, float* __restrict__ scores) {
  int i = blockIdx.x * 256 + threadIdx.x;
  if (i >= NB) return;
  int a = i / 1156;
  int rem = i - a * 1156;
  int y = rem / 34;
  int x = rem - y * 34;
  float fg = cls[(15 + a) * 1156 + rem];
  const float* p = pred + a * 4 * 1156 + rem;
  float t0 = p[0]    * (float)0.12677  + (float)0.000437;
  float t1 = p[1156] * (float)0.095741 + (float)0.002586;
  float t2 = p[2312] * (float)0.3173   + (float)-0.123953;
  float t3 = p[3468] * (float)0.281042 + (float)-0.081469;
  float aw = c_AW[a], ah = c_AH[a];
  float cx = t0 * aw + (float)x * 8.0f;
  float cy = t1 * ah + (float)y * 8.0f;
  float bw = expf(t2) * aw;
  float bh = expf(t3) * ah;
  float x1 = clipc(cx - 0.5f * (bw - 1.0f));
  float y1 = clipc(cy - 0.5f * (bh - 1.0f));
  float x2 = clipc(cx + 0.5f * (bw - 1.0f));
  float y2 = clipc(cy + 0.5f * (bh - 1.0f));
  boxes[i * 4 + 0] = x1;
  boxes[i * 4 + 1] = y1;
  boxes[i * 4 + 2] = x2;
  boxes[i * 4 + 3] = y2;
  float w2 = x2 - x1 + 1.0f, h2 = y2 - y1 + 1.0f;
  bool keep = (fg >= 0.2f) && ((w2 >= (float)6.16056) || (h2 >= (float)6.16056));
  scores[i] = keep ? fg : -1.0f;
}

// ---------------- Kernel 2: histogram top-3000 + bitonic sort + chunked greedy NMS ----------------
// Greedy scan over the descending-(score,idx)-sorted pool is exactly equivalent to the
// reference's 300-round argmax+suppress loop (same tie order via key = (score_map<<15)|(32767-idx)).
__global__ __launch_bounds__(256) void k_nms1(const float* __restrict__ boxes,
                                              const float* __restrict__ scores,
                                              float* __restrict__ dout,
                                              float* __restrict__ rois_xy,
                                              float* __restrict__ validf) {
  const int t = threadIdx.x;
  // 64KB region: hist u32[16384] (phase A) -> skey u64[4096] (phases B-D)
  __shared__ __align__(16) unsigned int hist[16384];
  unsigned long long* skey = (unsigned long long*)hist;
  __shared__ unsigned int coarse[256];
  __shared__ unsigned int bidx[1024];   // bucket-B member original idx
  __shared__ unsigned int bmap[1024];   // bucket-B member mapped score
  __shared__ int s_B, s_need, s_cB, s_n, s_A;
  __shared__ float4 abox[TOPK1 > 300 ? 300 : 300];  // accepted boxes
  __shared__ float aar[300];                        // accepted areas
  __shared__ unsigned int sup[64];

  // ---- Phase A: 14-bit histogram of mapped scores ----
  for (int b = t; b < 16384; b += 256) hist[b] = 0u;
  if (t == 0) { s_B = 0; s_need = 1; s_cB = 0; s_n = 0; s_A = 0; }
  __syncthreads();
  for (int i = t; i < NB; i += 256) atomicAdd(&hist[mapf(scores[i]) >> 18], 1u);
  __syncthreads();
  {
    unsigned s = 0;
    int b0 = t * 64;
    for (int b = 0; b < 64; ++b) s += hist[b0 + b];
    coarse[t] = s;
  }
  __syncthreads();
  if (t == 0) {
    unsigned acc = 0;
    int C = 0;
    unsigned nbefore = 0;
    for (int c = 255; c >= 0; --c) {
      if (acc + coarse[c] >= TOPK1) { C = c; nbefore = acc; break; }
      acc += coarse[c];
    }
    unsigned acc2 = nbefore;
    for (int b = C * 64 + 63; b >= C * 64; --b) {
      if (acc2 + hist[b] >= TOPK1) { s_B = b; s_need = TOPK1 - (int)acc2; break; }
      acc2 += hist[b];
    }
  }
  __syncthreads();
  const int B = s_B, need = s_need;

  // ---- Phase B: collect boundary bucket + compact bucket>B keys into skey ----
  // (skey overlays hist; hist is dead now)
  __syncthreads();
  for (int i = t; i < NB; i += 256) {
    unsigned m = mapf(scores[i]);
    int bk = (int)(m >> 18);
    if (bk > B) {
      int p = atomicAdd(&s_n, 1);
      if (p < 4096) skey[p] = ((unsigned long long)m << 15) | (unsigned)(32767 - i);
    } else if (bk == B) {
      int p = atomicAdd(&s_cB, 1);
      if (p < 1024) { bidx[p] = (unsigned)i; bmap[p] = m; }
    }
  }
  __syncthreads();
  const int cB = min(s_cB, 1024);
  // exact rank within boundary bucket; take top `need` by (score desc, idx asc)
  for (int p = t; p < cB; p += 256) {
    unsigned long long kp = ((unsigned long long)bmap[p] << 15) | (unsigned)(32767 - bidx[p]);
    int rank = 0;
    for (int q = 0; q < cB; ++q) {
      unsigned long long kq = ((unsigned long long)bmap[q] << 15) | (unsigned)(32767 - bidx[q]);
      rank += (kq > kp) ? 1 : 0;
    }
    if (rank < need) {
      int pos = atomicAdd(&s_n, 1);
      if (pos < 4096) skey[pos] = kp;
    }
  }
  __syncthreads();
  int nsel = min(s_n, 4096);
  for (int p = nsel + t; p < 4096; p += 256) skey[p] = 0ull;
  __syncthreads();

  // ---- Phase C: bitonic sort 4096 keys descending ----
  for (int k = 2; k <= 4096; k <<= 1) {
    for (int j = k >> 1; j > 0; j >>= 1) {
      for (int i = t; i < 4096; i += 256) {
        int l = i ^ j;
        if (l > i) {
          unsigned long long a = skey[i], b = skey[l];
          bool up = ((i & k) == 0);
          if ((a < b) == up) { skey[i] = b; skey[l] = a; }
        }
      }
      __syncthreads();
    }
  }

  // ---- Phase D: chunked greedy scan (64 candidates/chunk) ----
  int A = 0;
  for (int base = 0; base < TOPK1 && A < 300; base += 64) {
    int l = t & 63, w = t >> 6;
    int rank = base + l;
    bool active = (rank < TOPK1);
    unsigned long long key = active ? skey[rank] : 0ull;
    if (key == 0ull) active = false;
    int idx = 32767 - (int)(key & 32767ull);
    float4 bx = make_float4(0.f, 0.f, 0.f, 0.f);
    float sc = 0.f, area = 0.f;
    if (active) {
      bx = ((const float4*)boxes)[idx];
      sc = unmapf((unsigned)(key >> 15));
      area = (bx.z - bx.x + 1.0f) * (bx.w - bx.y + 1.0f);
    }
    if (t < 64) sup[t] = 0u;
    __syncthreads();
    // each wave checks a 4-way slice of the accepted set
    bool mysup = false;
    if (active) {
      for (int a = w; a < A; a += 4) {
        float4 ab = abox[a];
        float iw = fmaxf(fminf(bx.z, ab.z) - fmaxf(bx.x, ab.x) + 1.0f, 0.0f);
        float ih = fmaxf(fminf(bx.w, ab.w) - fmaxf(bx.y, ab.y) + 1.0f, 0.0f);
        float inter = iw * ih;
        float iou = inter / (area + aar[a] - inter);
        if (iou > 0.7f) { mysup = true; break; }
      }
    }
    if (mysup) sup[l] = 1u;
    __syncthreads();
    // wave 0: serial greedy within chunk
    if (t < 64) {
      bool alive = active && (sup[l] == 0u);
      unsigned long long bal = __ballot(alive);
      while (bal != 0ull && A < 300) {
        int j = __ffsll((unsigned long long)bal) - 1;  // lowest lane = highest key
        float jx1 = __shfl(bx.x, j), jy1 = __shfl(bx.y, j);
        float jx2 = __shfl(bx.z, j), jy2 = __shfl(bx.w, j);
        float jar = __shfl(area, j);
        if (l == j) {
          abox[A] = bx; aar[A] = area;
          dout[30 + A * 5 + 0] = 0.0f;
          dout[30 + A * 5 + 1] = bx.x;
          dout[30 + A * 5 + 2] = bx.y;
          dout[30 + A * 5 + 3] = bx.z;
          dout[30 + A * 5 + 4] = bx.w;
          dout[1530 + A] = sc;
          rois_xy[A * 4 + 0] = bx.x; rois_xy[A * 4 + 1] = bx.y;
          rois_xy[A * 4 + 2] = bx.z; rois_xy[A * 4 + 3] = bx.w;
          validf[A] = 1.0f;
        }
        if (alive) {
          float iw = fmaxf(fminf(bx.z, jx2) - fmaxf(bx.x, jx1) + 1.0f, 0.0f);
          float ih = fmaxf(fminf(bx.w, jy2) - fmaxf(bx.y, jy1) + 1.0f, 0.0f);
          float inter = iw * ih;
          float iou = inter / (area + jar - inter);
          if (iou > 0.7f || l == j) alive = false;  // winner self-kills (iou==1)
        }
        A++;
        bal = __ballot(alive);
      }
      if (l == 0) s_A = A;
    }
    __syncthreads();
    A = s_A;
  }
  // ---- zero-fill invalid tail rows ----
  for (int z = 30 + A * 5 + t; z < 1530; z += 256) dout[z] = 0.f;
  for (int z = 1530 + A + t; z < 1830; z += 256) dout[z] = 0.f;
  for (int z = A * 4 + t; z < 1200; z += 256) rois_xy[z] = 0.f;
  for (int z = A + t; z < 300; z += 256) validf[z] = 0.f;
}

// ---------------- Kernel 3: PSROI pooling (block per ROI) ----------------
__global__ __launch_bounds__(256) void k_psroi(const float* __restrict__ ft,
                                               const float* __restrict__ rois_xy,
                                               float* __restrict__ pooled) {
  int r = blockIdx.x;
  float r0 = rois_xy[r * 4 + 0], r1 = rois_xy[r * 4 + 1];
  float r2 = rois_xy[r * 4 + 2], r3 = rois_xy[r * 4 + 3];
  float sw = r0 * 0.125f;
  float sh = r1 * 0.125f;
  float ew = (r2 + 1.0f) * 0.125f;
  float eh = (r3 + 1.0f) * 0.125f;
  float rh = fmaxf(eh - sh, 0.1f);
  float rw = fmaxf(ew - sw, 0.1f);
  float bh = rh / 7.0f;
  float bwd = rw / 7.0f;
  for (int o = threadIdx.x; o < 490; o += 256) {
    int p = (o % 49) / 7;
    int q = o % 7;
    const float* base = ft + o * 1156;
    float acc = 0.f;
#pragma unroll
    for (int sy = 0; sy < 4; ++sy) {
      float ys = sh + (float)p * bh + ((float)sy + 0.5f) * (bh * 0.25f);
      float y0f = floorf(ys);
      float dy = ys - y0f;
      int y0 = (int)y0f;
      float wy0 = (1.0f - dy) * ((y0 >= 0 && y0 < 34) ? 1.f : 0.f);
      float wy1 = dy * ((y0 + 1 >= 0 && y0 + 1 < 34) ? 1.f : 0.f);
      int yc0 = min(max(y0, 0), 33), yc1 = min(max(y0 + 1, 0), 33);
#pragma unroll
      for (int sx = 0; sx < 4; ++sx) {
        float xs = sw + (float)q * bwd + ((float)sx + 0.5f) * (bwd * 0.25f);
        float x0f = floorf(xs);
        float dx = xs - x0f;
        int x0 = (int)x0f;
        float wx0 = (1.0f - dx) * ((x0 >= 0 && x0 < 34) ? 1.f : 0.f);
        float wx1 = dx * ((x0 + 1 >= 0 && x0 + 1 < 34) ? 1.f : 0.f);
        int xc0 = min(max(x0, 0), 33), xc1 = min(max(x0 + 1, 0), 33);
        float v00 = base[yc0 * 34 + xc0], v01 = base[yc0 * 34 + xc1];
        float v10 = base[yc1 * 34 + xc0], v11 = base[yc1 * 34 + xc1];
        acc += wy0 * wx0 * v00 + wy0 * wx1 * v01 + wy1 * wx0 * v10 + wy1 * wx1 * v11;
      }
    }
    pooled[r * 490 + o] = acc * (1.0f / 16.0f);
  }
}

// ---------------- Kernel 4: FC1 (490 -> 2048) + ReLU ----------------
__global__ __launch_bounds__(256) void k_fc1(const float* __restrict__ pooled,
                                             const float* __restrict__ Wi,
                                             const float* __restrict__ bi,
                                             float* __restrict__ feat) {
  __shared__ float pt[490][20];
  int t = threadIdx.x;
  int o = blockIdx.x * 256 + t;
  int r0 = blockIdx.y * 16;
  for (int idx = t; idx < 16 * 490; idx += 256) {
    int rr = idx / 490, kk = idx - rr * 490;
    pt[kk][rr] = (r0 + rr < 300) ? pooled[(r0 + rr) * 490 + kk] : 0.f;
  }
  __syncthreads();
  float acc[16];
#pragma unroll
  for (int e = 0; e < 16; ++e) acc[e] = 0.f;
  const float* wrow = Wi + o * 490;
  for (int k = 0; k < 490; ++k) {
    float wv = wrow[k];
    const float4* p4 = (const float4*)(&pt[k][0]);
    float4 a0 = p4[0], a1 = p4[1], a2 = p4[2], a3 = p4[3];
    acc[0] += wv * a0.x;  acc[1] += wv * a0.y;  acc[2] += wv * a0.z;  acc[3] += wv * a0.w;
    acc[4] += wv * a1.x;  acc[5] += wv * a1.y;  acc[6] += wv * a1.z;  acc[7] += wv * a1.w;
    acc[8] += wv * a2.x;  acc[9] += wv * a2.y;  acc[10] += wv * a2.z; acc[11] += wv * a2.w;
    acc[12] += wv * a3.x; acc[13] += wv * a3.y; acc[14] += wv * a3.z; acc[15] += wv * a3.w;
  }
  float bias = bi[o];
#pragma unroll
  for (int e = 0; e < 16; ++e) {
    int rr = r0 + e;
    if (rr < 300) feat[rr * 2048 + o] = fmaxf(acc[e] + bias, 0.f);
  }
}

// ---------------- Kernel 5: FC2 heads + softmax + per-class decode ----------------
__global__ __launch_bounds__(256) void k_fc2d(const float* __restrict__ feat,
                                              const float* __restrict__ Wc,
                                              const float* __restrict__ bc,
                                              const float* __restrict__ Wb,
                                              const float* __restrict__ bb,
                                              const float* __restrict__ rois_xy,
                                              const float* __restrict__ validf,
                                              float* __restrict__ db2,
                                              float* __restrict__ msc2) {
  int r = blockIdx.x;
  int t = threadIdx.x;
  int oid = t & 31, part = t >> 5;
  __shared__ float red[8][33];
  __shared__ float s_logit[20];
  __shared__ float s_probs[4];
  float partial = 0.f;
  if (oid < 20) {
    const float* frow = feat + r * 2048 + part * 256;
    const float* wrow = (oid < 4 ? Wc + oid * 2048 : Wb + (oid - 4) * 2048) + part * 256;
    for (int k = 0; k < 256; ++k) partial += frow[k] * wrow[k];
  }
  red[part][oid] = partial;
  __syncthreads();
  if (t < 20) {
    float s = 0.f;
    for (int pz = 0; pz < 8; ++pz) s += red[pz][t];
    s_logit[t] = s + (t < 4 ? bc[t] : bb[t - 4]);
  }
  __syncthreads();
  if (t == 0) {
    float m = fmaxf(fmaxf(s_logit[0], s_logit[1]), fmaxf(s_logit[2], s_logit[3]));
    float e0 = expf(s_logit[0] - m), e1 = expf(s_logit[1] - m);
    float e2 = expf(s_logit[2] - m), e3 = expf(s_logit[3] - m);
    float ssum = e0 + e1 + e2 + e3;
    s_probs[0] = e0 / ssum; s_probs[1] = e1 / ssum;
    s_probs[2] = e2 / ssum; s_probs[3] = e3 / ssum;
  }
  __syncthreads();
  if (t < 3) {
    int c = t + 1;
    float x1 = rois_xy[r * 4 + 0], y1 = rois_xy[r * 4 + 1];
    float x2 = rois_xy[r * 4 + 2], y2 = rois_xy[r * 4 + 3];
    float rwv = x2 - x1 + 1.0f, rhv = y2 - y1 + 1.0f;
    float rcx = x1 + 0.5f * (rwv - 1.0f), rcy = y1 + 0.5f * (rhv - 1.0f);
    float t0 = s_logit[4 + 4 * c + 0] * 0.1f;
    float t1 = s_logit[4 + 4 * c + 1] * 0.1f;
    float t2 = s_logit[4 + 4 * c + 2] * 0.2f;
    float t3 = s_logit[4 + 4 * c + 3] * 0.2f;
    float cx = t0 * rwv + rcx, cy = t1 * rhv + rcy;
    float bw = expf(t2) * rwv, bh = expf(t3) * rhv;
    float dx1 = clipc(cx - 0.5f * (bw - 1.0f));
    float dy1 = clipc(cy - 0.5f * (bh - 1.0f));
    float dx2 = clipc(cx + 0.5f * (bw - 1.0f));
    float dy2 = clipc(cy + 0.5f * (bh - 1.0f));
    float dw = dx2 - dx1 + 1.0f, dh = dy2 - dy1 + 1.0f;
    float sc = s_probs[c];
    bool objok = (1.0f - s_probs[0]) >= 0.1f;
    bool valid = validf[r] > 0.5f;
    bool kf = valid && objok && (sc >= 0.1f) && ((dw >= (float)8.8008) || (dh >= (float)8.8008));
    int i2 = (c - 1) * 300 + r;
    db2[i2 * 4 + 0] = dx1; db2[i2 * 4 + 1] = dy1;
    db2[i2 * 4 + 2] = dx2; db2[i2 * 4 + 3] = dy2;
    msc2[i2] = kf ? sc : -1.0f;
  }
}

// ---------------- Kernel 6: exact top-300 of 900 + NMS 5 -> bboxes ----------------
__global__ __launch_bounds__(256) void k_nms2(const float* __restrict__ db2,
                                              const float* __restrict__ msc2,
                                              float* __restrict__ dout) {
  const int t = threadIdx.x;
  __shared__ int s_wsum[4];
  __shared__ unsigned long long wred[4];
  __shared__ int s_take;
  __shared__ int s_rem;
  __shared__ unsigned long long s_pref;
  __shared__ int s_cnt;
  __shared__ int s_idx[TOPK2];
  __shared__ float s_box[5];

  unsigned long long key[4];
#pragma unroll
  for (int j = 0; j < 4; ++j) {
    int i = t + j * 256;
    key[j] = (i < 900) ? (((unsigned long long)mapf(msc2[i]) << 10) | (unsigned)(1023 - i)) : 0ull;
  }
  unsigned act = 0xFu;
  if (t == 0) { s_rem = TOPK2; s_pref = 0ull; }
  __syncthreads();
  for (int b = 41; b >= 0; --b) {
    int c = 0;
#pragma unroll
    for (int j = 0; j < 4; ++j)
      if ((act >> j) & 1u) c += (int)((key[j] >> b) & 1ull);
    for (int off = 32; off > 0; off >>= 1) c += __shfl_xor(c, off);
    if ((t & 63) == 0) s_wsum[t >> 6] = c;
    __syncthreads();
    if (t == 0) {
      int tot = s_wsum[0] + s_wsum[1] + s_wsum[2] + s_wsum[3];
      if (tot >= s_rem) { s_take = 1; s_pref |= (1ull << b); }
      else { s_take = 0; s_rem -= tot; }
    }
    __syncthreads();
    int take = s_take;
#pragma unroll
    for (int j = 0; j < 4; ++j)
      if ((act >> j) & 1u)
        if ((int)((key[j] >> b) & 1ull) != take) act &= ~(1u << j);
  }
  unsigned long long cutoff = s_pref;
  if (t == 0) s_cnt = 0;
  __syncthreads();
#pragma unroll
  for (int j = 0; j < 4; ++j)
    if (key[j] >= cutoff) { int p = atomicAdd(&s_cnt, 1); s_idx[p] = t + j * 256; }
  __syncthreads();

  float ex1[2], ey1[2], ex2[2], ey2[2], esc[2], ear[2], elab[2];
  int eidx[2];
  bool ealive[2];
#pragma unroll
  for (int e = 0; e < 2; ++e) {
    int pos = t + e * 256;
    ealive[e] = false; eidx[e] = -1;
    ex1[e] = ey1[e] = ex2[e] = ey2[e] = ear[e] = elab[e] = 0.f; esc[e] = -2.f;
    if (pos < TOPK2) {
      int idx = s_idx[pos];
      ex1[e] = db2[idx * 4 + 0]; ey1[e] = db2[idx * 4 + 1];
      ex2[e] = db2[idx * 4 + 2]; ey2[e] = db2[idx * 4 + 3];
      esc[e] = msc2[idx];
      ear[e] = (ex2[e] - ex1[e] + 1.0f) * (ey2[e] - ey1[e] + 1.0f);
      elab[e] = (float)(idx / 300 + 1);
      eidx[e] = idx; ealive[e] = true;
    }
  }
  int r = 0;
  for (; r < ROUNDS2; ++r) {
    unsigned long long best = 0ull;
#pragma unroll
    for (int e = 0; e < 2; ++e)
      if (ealive[e]) {
        unsigned long long k = ((unsigned long long)mapf(esc[e]) << 10) | (unsigned)(1023 - eidx[e]);
        if (k > best) best = k;
      }
    for (int off = 32; off > 0; off >>= 1) {
      unsigned long long o = shflxor64(best, off);
      if (o > best) best = o;
    }
    if ((t & 63) == 0) wred[t >> 6] = best;
    __syncthreads();
    unsigned long long bk = wred[0];
    for (int w = 1; w < 4; ++w) if (wred[w] > bk) bk = wred[w];
    float bsc = unmapf((unsigned)(bk >> 10));
    bool bvalid = (bsc > 0.0f);
    int widx = 1023 - (int)(bk & 1023ull);
#pragma unroll
    for (int e = 0; e < 2; ++e) {
      if (ealive[e] && eidx[e] == widx) {
        s_box[0] = ex1[e]; s_box[1] = ey1[e]; s_box[2] = ex2[e]; s_box[3] = ey2[e]; s_box[4] = ear[e];
        if (bvalid) {
          dout[r * 6 + 0] = ex1[e]; dout[r * 6 + 1] = ey1[e];
          dout[r * 6 + 2] = ex2[e]; dout[r * 6 + 3] = ey2[e];
          dout[r * 6 + 4] = esc[e]; dout[r * 6 + 5] = elab[e];
        }
      }
    }
    __syncthreads();
    if (!bvalid) break;
    float bx1 = s_box[0], by1 = s_box[1], bx2 = s_box[2], by2 = s_box[3], ba = s_box[4];
#pragma unroll
    for (int e = 0; e < 2; ++e)
      if (ealive[e]) {
        float iw = fmaxf(fminf(ex2[e], bx2) - fmaxf(ex1[e], bx1) + 1.0f, 0.0f);
        float ih = fmaxf(fminf(ey2[e], by2) - fmaxf(ey1[e], by1) + 1.0f, 0.0f);
        float inter = iw * ih;
        float iou = inter / (ear[e] + ba - inter);
        if (iou > 0.5f) ealive[e] = false;
      }
  }
  if (r < ROUNDS2) {
    for (int z = r * 6 + t; z < 30; z += 256) dout[z] = 0.f;
  }
}

extern "C" void kernel_launch(void* const* d_in, const int* in_sizes, int n_in,
                              void* d_out, int out_size, void* d_ws, size_t ws_size,
                              hipStream_t stream) {
  const float* cls  = (const float*)d_in[0];
  const float* pred = (const float*)d_in[1];
  const float* ft   = (const float*)d_in[2];
  const float* Wi   = (const float*)d_in[3];
  const float* bi   = (const float*)d_in[4];
  const float* Wc   = (const float*)d_in[5];
  const float* bc   = (const float*)d_in[6];
  const float* Wb   = (const float*)d_in[7];
  const float* bb   = (const float*)d_in[8];
  float* out = (float*)d_out;
  float* w = (float*)d_ws;
  float* boxes   = w;              // 17340*4 = 69360
  float* scores  = w + 69360;      // 17340          -> 86700
  float* rois_xy = w + 86700;      // 300*4 = 1200   -> 87900
  float* validf  = w + 87900;      // 300            -> 88200
  float* pooled  = w + 88200;      // 300*490=147000 -> 235200
  float* feat    = w + 235200;     // 300*2048=614400-> 849600
  float* db2     = w + 849600;     // 900*4 = 3600   -> 853200
  float* msc2    = w + 853200;     // 900            -> 854100 floats (~3.42 MB)

  k_decode<<<68, 256, 0, stream>>>(cls, pred, boxes, scores);
  k_nms1<<<1, 256, 0, stream>>>(boxes, scores, out, rois_xy, validf);
  k_psroi<<<300, 256, 0, stream>>>(ft, rois_xy, pooled);
  k_fc1<<<dim3(8, 19), 256, 0, stream>>>(pooled, Wi, bi, feat);
  k_fc2d<<<300, 256, 0, stream>>>(feat, Wc, bc, Wb, bb, rois_xy, validf, db2, msc2);
  k_nms2<<<1, 256, 0, stream>>>(db2, msc2, out);
}

// Round 3
// 309.013 us; speedup vs baseline: 2.8692x; 1.3995x over previous
//
#include <hip/hip_runtime.h>

#define NB 17340      // 15*34*34
#define TOPK1 3000
#define TOPK2 300

__constant__ float c_AW[15] = {9.232984, 16.0, 27.712813, 18.465969, 32.0, 55.425626,
                               36.931937, 64.0, 110.851252, 73.863875, 128.0, 221.702503,
                               147.72775, 256.0, 443.405007};
__constant__ float c_AH[15] = {27.72668, 16.0, 9.237604, 55.453359, 32.0, 18.475209,
                               110.906719, 64.0, 36.950417, 221.813438, 128.0, 73.900834,
                               443.626876, 256.0, 147.801669};

__device__ __forceinline__ unsigned mapf(float f) {
  unsigned u = __float_as_uint(f);
  return (u & 0x80000000u) ? ~u : (u | 0x80000000u);
}
__device__ __forceinline__ float unmapf(unsigned m) {
  unsigned u = (m & 0x80000000u) ? (m & 0x7FFFFFFFu) : ~m;
  return __uint_as_float(u);
}
__device__ __forceinline__ float clipc(float v) {
  return fminf(fmaxf(v, 0.0f), 269.0f);
}

// ---------------- Kernel 1: RPN decode + keep filter + global histogram ----------------
__global__ void k_decode(const float* __restrict__ cls, const float* __restrict__ pred,
                         float* __restrict__ boxes, float* __restrict__ scores,
                         unsigned int* __restrict__ hist) {
  int i = blockIdx.x * 256 + threadIdx.x;
  if (i >= NB) return;
  int a = i / 1156;
  int rem = i - a * 1156;
  int y = rem / 34;
  int x = rem - y * 34;
  float fg = cls[(15 + a) * 1156 + rem];
  const float* p = pred + a * 4 * 1156 + rem;
  float t0 = p[0]    * (float)0.12677  + (float)0.000437;
  float t1 = p[1156] * (float)0.095741 + (float)0.002586;
  float t2 = p[2312] * (float)0.3173   + (float)-0.123953;
  float t3 = p[3468] * (float)0.281042 + (float)-0.081469;
  float aw = c_AW[a], ah = c_AH[a];
  float cx = t0 * aw + (float)x * 8.0f;
  float cy = t1 * ah + (float)y * 8.0f;
  float bw = expf(t2) * aw;
  float bh = expf(t3) * ah;
  float x1 = clipc(cx - 0.5f * (bw - 1.0f));
  float y1 = clipc(cy - 0.5f * (bh - 1.0f));
  float x2 = clipc(cx + 0.5f * (bw - 1.0f));
  float y2 = clipc(cy + 0.5f * (bh - 1.0f));
  boxes[i * 4 + 0] = x1;
  boxes[i * 4 + 1] = y1;
  boxes[i * 4 + 2] = x2;
  boxes[i * 4 + 3] = y2;
  float w2 = x2 - x1 + 1.0f, h2 = y2 - y1 + 1.0f;
  bool keep = (fg >= 0.2f) && ((w2 >= (float)6.16056) || (h2 >= (float)6.16056));
  scores[i] = keep ? fg : -1.0f;
  // masked (-1) entries skipped: they all share one bucket far below the cutoff,
  // and kept-count >> 3000 so the boundary is always inside the kept range.
  if (keep) atomicAdd(&hist[mapf(fg) >> 18], 1u);
}

// ---------------- Kernel 2: redundant cutoff + parallel compact ----------------
// Every block computes the same boundary bucket B from the (L2-hot) histogram, then
// compacts its slice of keys with bucket >= B into the global key array (order-free).
__global__ __launch_bounds__(256) void k_compact(const float* __restrict__ scores,
                                                 const unsigned int* __restrict__ hist,
                                                 unsigned int* __restrict__ cnt,
                                                 unsigned long long* __restrict__ keys) {
  const int t = threadIdx.x;
  __shared__ unsigned int sh[16384];
  __shared__ unsigned int coarse[256];
  __shared__ int s_B;
  for (int i = t; i < 16384; i += 256) sh[i] = hist[i];
  __syncthreads();
  {
    unsigned s = 0;
    int b0 = t * 64;
    for (int b = 0; b < 64; ++b) s += sh[b0 + b];
    coarse[t] = s;
  }
  __syncthreads();
  if (t == 0) {
    unsigned acc = 0, nbefore = 0;
    int C = 0;
    for (int c = 255; c >= 0; --c) {
      if (acc + coarse[c] >= (unsigned)TOPK1) { C = c; nbefore = acc; break; }
      acc += coarse[c];
    }
    unsigned acc2 = nbefore;
    int B = C * 64;
    for (int b = C * 64 + 63; b >= C * 64; --b) {
      if (acc2 + sh[b] >= (unsigned)TOPK1) { B = b; break; }
      acc2 += sh[b];
    }
    s_B = B;
  }
  __syncthreads();
  const unsigned B = (unsigned)s_B;
  int i = blockIdx.x * 256 + t;
  if (i < NB) {
    unsigned m = mapf(scores[i]);
    if ((m >> 18) >= B) {
      unsigned p = atomicAdd(cnt, 1u);
      if (p < 4096u) keys[p] = ((unsigned long long)m << 15) | (unsigned)(32767 - i);
    }
  }
}

// ---------------- Kernel 3: bitonic sort 4096 + greedy NMS-300 ----------------
// Greedy scan over the descending-(score,idx)-sorted pool == reference 300-round argmax loop.
__global__ __launch_bounds__(1024) void k_nms1(const float* __restrict__ boxes,
                                               const unsigned int* __restrict__ cnt,
                                               const unsigned long long* __restrict__ keys,
                                               float* __restrict__ dout,
                                               float* __restrict__ rois_xy,
                                               float* __restrict__ validf) {
  const int t = threadIdx.x;
  __shared__ unsigned long long skey[4096];   // 32 KB
  __shared__ float4 abox[300];
  __shared__ float aar[300];
  __shared__ unsigned int sup[64];
  __shared__ int s_A;
  const int K = min((int)cnt[0], 4096);
  for (int i = t; i < 4096; i += 1024) skey[i] = (i < K) ? keys[i] : 0ull;
  if (t == 0) s_A = 0;
  __syncthreads();
  // bitonic, descending
  for (int k = 2; k <= 4096; k <<= 1) {
    for (int j = k >> 1; j > 0; j >>= 1) {
      for (int i = t; i < 4096; i += 1024) {
        int l = i ^ j;
        if (l > i) {
          unsigned long long a = skey[i], b = skey[l];
          bool up = ((i & k) == 0);
          if ((a < b) == up) { skey[i] = b; skey[l] = a; }
        }
      }
      __syncthreads();
    }
  }
  // chunked greedy scan: 64 candidates/chunk; 16 waves slice the accepted-set check
  int A = 0;
  const int l = t & 63, w = t >> 6;
  for (int base = 0; base < TOPK1; base += 64) {
    if (A >= 300) break;
    unsigned headm = (unsigned)(skey[base] >> 15);
    if (headm <= 0x80000000u) break;   // head score <= 0: nothing acceptable remains
    int rank = base + l;
    unsigned long long key = skey[rank];
    unsigned mk = (unsigned)(key >> 15);
    bool active = (rank < TOPK1) && (mk > 0x80000000u);
    int idx = 32767 - (int)(key & 32767ull);
    float4 bx = make_float4(0.f, 0.f, 0.f, 0.f);
    float area = 0.f;
    if (active) {
      bx = ((const float4*)boxes)[idx];
      area = (bx.z - bx.x + 1.0f) * (bx.w - bx.y + 1.0f);
    }
    if (t < 64) sup[t] = 0u;
    __syncthreads();
    if (active) {
      for (int a = w; a < A; a += 16) {
        float4 ab = abox[a];
        float iw = fmaxf(fminf(bx.z, ab.z) - fmaxf(bx.x, ab.x) + 1.0f, 0.0f);
        float ih = fmaxf(fminf(bx.w, ab.w) - fmaxf(bx.y, ab.y) + 1.0f, 0.0f);
        float inter = iw * ih;
        float iou = inter / (area + aar[a] - inter);
        if (iou > 0.7f) { sup[l] = 1u; break; }
      }
    }
    __syncthreads();
    if (t < 64) {   // wave 0: in-chunk serial greedy
      bool alive = active && (sup[l] == 0u);
      unsigned long long bal = __ballot(alive);
      while (bal != 0ull && A < 300) {
        int j = __ffsll((unsigned long long)bal) - 1;  // lowest lane = highest key
        float jx1 = __shfl(bx.x, j), jy1 = __shfl(bx.y, j);
        float jx2 = __shfl(bx.z, j), jy2 = __shfl(bx.w, j);
        float jar = __shfl(area, j);
        if (l == j) {
          abox[A] = bx; aar[A] = area;
          dout[30 + A * 5 + 0] = 0.0f;
          dout[30 + A * 5 + 1] = bx.x;
          dout[30 + A * 5 + 2] = bx.y;
          dout[30 + A * 5 + 3] = bx.z;
          dout[30 + A * 5 + 4] = bx.w;
          dout[1530 + A] = unmapf(mk);
          rois_xy[A * 4 + 0] = bx.x; rois_xy[A * 4 + 1] = bx.y;
          rois_xy[A * 4 + 2] = bx.z; rois_xy[A * 4 + 3] = bx.w;
          validf[A] = 1.0f;
        }
        if (alive) {
          float iw = fmaxf(fminf(bx.z, jx2) - fmaxf(bx.x, jx1) + 1.0f, 0.0f);
          float ih = fmaxf(fminf(bx.w, jy2) - fmaxf(bx.y, jy1) + 1.0f, 0.0f);
          float inter = iw * ih;
          float iou = inter / (area + jar - inter);
          if (iou > 0.7f || l == j) alive = false;  // winner self-kills
        }
        A++;
        bal = __ballot(alive);
      }
      if (l == 0) s_A = A;
    }
    __syncthreads();
    A = s_A;
  }
  for (int z = 30 + A * 5 + t; z < 1530; z += 1024) dout[z] = 0.f;
  for (int z = 1530 + A + t; z < 1830; z += 1024) dout[z] = 0.f;
  for (int z = A * 4 + t; z < 1200; z += 1024) rois_xy[z] = 0.f;
  for (int z = A + t; z < 300; z += 1024) validf[z] = 0.f;
}

// ---------------- Kernel 4: PSROI pooling (block per ROI) ----------------
__global__ __launch_bounds__(256) void k_psroi(const float* __restrict__ ft,
                                               const float* __restrict__ rois_xy,
                                               float* __restrict__ pooled) {
  int r = blockIdx.x;
  float r0 = rois_xy[r * 4 + 0], r1 = rois_xy[r * 4 + 1];
  float r2 = rois_xy[r * 4 + 2], r3 = rois_xy[r * 4 + 3];
  float sw = r0 * 0.125f;
  float sh = r1 * 0.125f;
  float ew = (r2 + 1.0f) * 0.125f;
  float eh = (r3 + 1.0f) * 0.125f;
  float rh = fmaxf(eh - sh, 0.1f);
  float rw = fmaxf(ew - sw, 0.1f);
  float bh = rh / 7.0f;
  float bwd = rw / 7.0f;
  for (int o = threadIdx.x; o < 490; o += 256) {
    int p = (o % 49) / 7;
    int q = o % 7;
    const float* base = ft + o * 1156;
    float acc = 0.f;
#pragma unroll
    for (int sy = 0; sy < 4; ++sy) {
      float ys = sh + (float)p * bh + ((float)sy + 0.5f) * (bh * 0.25f);
      float y0f = floorf(ys);
      float dy = ys - y0f;
      int y0 = (int)y0f;
      float wy0 = (1.0f - dy) * ((y0 >= 0 && y0 < 34) ? 1.f : 0.f);
      float wy1 = dy * ((y0 + 1 >= 0 && y0 + 1 < 34) ? 1.f : 0.f);
      int yc0 = min(max(y0, 0), 33), yc1 = min(max(y0 + 1, 0), 33);
#pragma unroll
      for (int sx = 0; sx < 4; ++sx) {
        float xs = sw + (float)q * bwd + ((float)sx + 0.5f) * (bwd * 0.25f);
        float x0f = floorf(xs);
        float dx = xs - x0f;
        int x0 = (int)x0f;
        float wx0 = (1.0f - dx) * ((x0 >= 0 && x0 < 34) ? 1.f : 0.f);
        float wx1 = dx * ((x0 + 1 >= 0 && x0 + 1 < 34) ? 1.f : 0.f);
        int xc0 = min(max(x0, 0), 33), xc1 = min(max(x0 + 1, 0), 33);
        float v00 = base[yc0 * 34 + xc0], v01 = base[yc0 * 34 + xc1];
        float v10 = base[yc1 * 34 + xc0], v11 = base[yc1 * 34 + xc1];
        acc += wy0 * wx0 * v00 + wy0 * wx1 * v01 + wy1 * wx0 * v10 + wy1 * wx1 * v11;
      }
    }
    pooled[r * 490 + o] = acc * (1.0f / 16.0f);
  }
}

// ---------------- Kernel 5: FC1 (490 -> 2048) + ReLU ----------------
__global__ __launch_bounds__(256) void k_fc1(const float* __restrict__ pooled,
                                             const float* __restrict__ Wi,
                                             const float* __restrict__ bi,
                                             float* __restrict__ feat) {
  __shared__ float pt[490][20];
  int t = threadIdx.x;
  int o = blockIdx.x * 256 + t;
  int r0 = blockIdx.y * 16;
  for (int idx = t; idx < 16 * 490; idx += 256) {
    int rr = idx / 490, kk = idx - rr * 490;
    pt[kk][rr] = (r0 + rr < 300) ? pooled[(r0 + rr) * 490 + kk] : 0.f;
  }
  __syncthreads();
  float acc[16];
#pragma unroll
  for (int e = 0; e < 16; ++e) acc[e] = 0.f;
  const float2* wrow2 = (const float2*)(Wi + o * 490);   // o*490 even -> 8B aligned
  for (int k2 = 0; k2 < 245; ++k2) {
    float2 wv = wrow2[k2];
    int k = k2 * 2;
    const float4* p4a = (const float4*)(&pt[k][0]);
    const float4* p4b = (const float4*)(&pt[k + 1][0]);
    float4 a0 = p4a[0], a1 = p4a[1], a2 = p4a[2], a3 = p4a[3];
    float4 b0 = p4b[0], b1 = p4b[1], b2 = p4b[2], b3 = p4b[3];
    acc[0] += wv.x * a0.x + wv.y * b0.x;  acc[1] += wv.x * a0.y + wv.y * b0.y;
    acc[2] += wv.x * a0.z + wv.y * b0.z;  acc[3] += wv.x * a0.w + wv.y * b0.w;
    acc[4] += wv.x * a1.x + wv.y * b1.x;  acc[5] += wv.x * a1.y + wv.y * b1.y;
    acc[6] += wv.x * a1.z + wv.y * b1.z;  acc[7] += wv.x * a1.w + wv.y * b1.w;
    acc[8] += wv.x * a2.x + wv.y * b2.x;  acc[9] += wv.x * a2.y + wv.y * b2.y;
    acc[10] += wv.x * a2.z + wv.y * b2.z; acc[11] += wv.x * a2.w + wv.y * b2.w;
    acc[12] += wv.x * a3.x + wv.y * b3.x; acc[13] += wv.x * a3.y + wv.y * b3.y;
    acc[14] += wv.x * a3.z + wv.y * b3.z; acc[15] += wv.x * a3.w + wv.y * b3.w;
  }
  float bias = bi[o];
#pragma unroll
  for (int e = 0; e < 16; ++e) {
    int rr = r0 + e;
    if (rr < 300) feat[rr * 2048 + o] = fmaxf(acc[e] + bias, 0.f);
  }
}

// ---------------- Kernel 6: FC2 heads + softmax + per-class decode (fused) ----------------
__global__ __launch_bounds__(256) void k_fc2(const float* __restrict__ feat,
                                             const float* __restrict__ Wc,
                                             const float* __restrict__ bc,
                                             const float* __restrict__ Wb,
                                             const float* __restrict__ bb,
                                             const float* __restrict__ rois_xy,
                                             const float* __restrict__ validf,
                                             float* __restrict__ db2,
                                             float* __restrict__ msc2) {
  int r = blockIdx.x;
  int t = threadIdx.x;
  int l = t & 63, w = t >> 6;
  __shared__ float frow[2048];
  __shared__ float s_logit[20];
  __shared__ float s_probs[4];
  for (int i = t; i < 512; i += 256)
    ((float4*)frow)[i] = ((const float4*)(feat + r * 2048))[i];
  __syncthreads();
  for (int o = w; o < 20; o += 4) {
    const float* wr = (o < 4) ? (Wc + o * 2048) : (Wb + (o - 4) * 2048);
    float p = 0.f;
#pragma unroll
    for (int j = 0; j < 8; ++j) {
      float4 wv = ((const float4*)wr)[l + 64 * j];
      float4 fv = ((const float4*)frow)[l + 64 * j];
      p += wv.x * fv.x + wv.y * fv.y + wv.z * fv.z + wv.w * fv.w;
    }
    for (int off = 32; off > 0; off >>= 1) p += __shfl_xor(p, off);
    if (l == 0) s_logit[o] = p + ((o < 4) ? bc[o] : bb[o - 4]);
  }
  __syncthreads();
  if (t == 0) {
    float m = fmaxf(fmaxf(s_logit[0], s_logit[1]), fmaxf(s_logit[2], s_logit[3]));
    float e0 = expf(s_logit[0] - m), e1 = expf(s_logit[1] - m);
    float e2 = expf(s_logit[2] - m), e3 = expf(s_logit[3] - m);
    float ssum = e0 + e1 + e2 + e3;
    s_probs[0] = e0 / ssum; s_probs[1] = e1 / ssum;
    s_probs[2] = e2 / ssum; s_probs[3] = e3 / ssum;
  }
  __syncthreads();
  if (t < 3) {
    int c = t + 1;
    float x1 = rois_xy[r * 4 + 0], y1 = rois_xy[r * 4 + 1];
    float x2 = rois_xy[r * 4 + 2], y2 = rois_xy[r * 4 + 3];
    float rwv = x2 - x1 + 1.0f, rhv = y2 - y1 + 1.0f;
    float rcx = x1 + 0.5f * (rwv - 1.0f), rcy = y1 + 0.5f * (rhv - 1.0f);
    float t0 = s_logit[4 + 4 * c + 0] * 0.1f;
    float t1 = s_logit[4 + 4 * c + 1] * 0.1f;
    float t2 = s_logit[4 + 4 * c + 2] * 0.2f;
    float t3 = s_logit[4 + 4 * c + 3] * 0.2f;
    float cx = t0 * rwv + rcx, cy = t1 * rhv + rcy;
    float bw = expf(t2) * rwv, bh = expf(t3) * rhv;
    float dx1 = clipc(cx - 0.5f * (bw - 1.0f));
    float dy1 = clipc(cy - 0.5f * (bh - 1.0f));
    float dx2 = clipc(cx + 0.5f * (bw - 1.0f));
    float dy2 = clipc(cy + 0.5f * (bh - 1.0f));
    float dw = dx2 - dx1 + 1.0f, dh = dy2 - dy1 + 1.0f;
    float sc = s_probs[c];
    bool objok = (1.0f - s_probs[0]) >= 0.1f;
    bool valid = validf[r] > 0.5f;
    bool kf = valid && objok && (sc >= 0.1f) && ((dw >= (float)8.8008) || (dh >= (float)8.8008));
    int i2 = (c - 1) * 300 + r;
    db2[i2 * 4 + 0] = dx1; db2[i2 * 4 + 1] = dy1;
    db2[i2 * 4 + 2] = dx2; db2[i2 * 4 + 3] = dy2;
    msc2[i2] = kf ? sc : -1.0f;
  }
}

// ---------------- Kernel 7: sort 900 + greedy NMS-5 -> bboxes ----------------
__global__ __launch_bounds__(1024) void k_nms2(const float* __restrict__ db2,
                                               const float* __restrict__ msc2,
                                               float* __restrict__ dout) {
  const int t = threadIdx.x;
  __shared__ unsigned long long skey[1024];
  __shared__ float4 abox[5];
  __shared__ float aar[5];
  __shared__ int s_A;
  skey[t] = (t < 900) ? (((unsigned long long)mapf(msc2[t]) << 10) | (unsigned)(1023 - t)) : 0ull;
  if (t == 0) s_A = 0;
  __syncthreads();
  for (int k = 2; k <= 1024; k <<= 1) {
    for (int j = k >> 1; j > 0; j >>= 1) {
      int i = t, l2 = i ^ j;
      if (l2 > i) {
        unsigned long long a = skey[i], b = skey[l2];
        bool up = ((i & k) == 0);
        if ((a < b) == up) { skey[i] = b; skey[l2] = a; }
      }
      __syncthreads();
    }
  }
  if (t < 64) {
    int A = 0;
    for (int base = 0; base < TOPK2 && A < 5; base += 64) {
      unsigned headm = (unsigned)(skey[base] >> 10);
      if (headm <= 0x80000000u) break;
      int rank = base + t;
      unsigned long long key = skey[rank];
      unsigned mk = (unsigned)(key >> 10);
      bool active = (rank < TOPK2) && (mk > 0x80000000u);
      int idx = 1023 - (int)(key & 1023ull);
      float4 bx = make_float4(0.f, 0.f, 0.f, 0.f);
      float area = 0.f;
      if (active) {
        bx = ((const float4*)db2)[idx];
        area = (bx.z - bx.x + 1.0f) * (bx.w - bx.y + 1.0f);
      }
      bool alive = active;
      for (int a = 0; a < A; ++a) {
        float4 ab = abox[a];
        float iw = fmaxf(fminf(bx.z, ab.z) - fmaxf(bx.x, ab.x) + 1.0f, 0.0f);
        float ih = fmaxf(fminf(bx.w, ab.w) - fmaxf(bx.y, ab.y) + 1.0f, 0.0f);
        float inter = iw * ih;
        float iou = inter / (area + aar[a] - inter);
        if (iou > 0.5f) { alive = false; break; }
      }
      unsigned long long bal = __ballot(alive);
      while (bal != 0ull && A < 5) {
        int j = __ffsll((unsigned long long)bal) - 1;
        float jx1 = __shfl(bx.x, j), jy1 = __shfl(bx.y, j);
        float jx2 = __shfl(bx.z, j), jy2 = __shfl(bx.w, j);
        float jar = __shfl(area, j);
        if (t == j) {
          abox[A] = bx; aar[A] = area;
          dout[A * 6 + 0] = bx.x; dout[A * 6 + 1] = bx.y;
          dout[A * 6 + 2] = bx.z; dout[A * 6 + 3] = bx.w;
          dout[A * 6 + 4] = unmapf(mk);
          dout[A * 6 + 5] = (float)(idx / 300 + 1);
        }
        if (alive) {
          float iw = fmaxf(fminf(bx.z, jx2) - fmaxf(bx.x, jx1) + 1.0f, 0.0f);
          float ih = fmaxf(fminf(bx.w, jy2) - fmaxf(bx.y, jy1) + 1.0f, 0.0f);
          float inter = iw * ih;
          float iou = inter / (area + jar - inter);
          if (iou > 0.5f || t == j) alive = false;
        }
        A++;
        bal = __ballot(alive);
      }
    }
    if (t == 0) s_A = A;
  }
  __syncthreads();
  int A = s_A;
  for (int z = A * 6 + t; z < 30; z += 1024) dout[z] = 0.f;
}

extern "C" void kernel_launch(void* const* d_in, const int* in_sizes, int n_in,
                              void* d_out, int out_size, void* d_ws, size_t ws_size,
                              hipStream_t stream) {
  const float* cls  = (const float*)d_in[0];
  const float* pred = (const float*)d_in[1];
  const float* ft   = (const float*)d_in[2];
  const float* Wi   = (const float*)d_in[3];
  const float* bi   = (const float*)d_in[4];
  const float* Wc   = (const float*)d_in[5];
  const float* bc   = (const float*)d_in[6];
  const float* Wb   = (const float*)d_in[7];
  const float* bb   = (const float*)d_in[8];
  float* out = (float*)d_out;
  float* w = (float*)d_ws;
  // layout (float offsets)
  float* boxes   = w;                                   // 0      .. 69360
  float* scores  = w + 69360;                           // 69360  .. 86700
  unsigned int* hist = (unsigned int*)(w + 86700);      // 86700  .. 103084
  unsigned int* cnt  = (unsigned int*)(w + 103084);     // 103084 .. 103085
  unsigned long long* keys = (unsigned long long*)(w + 103088); // 8B-aligned, 4096 u64 -> 111280
  float* rois_xy = w + 111280;                          // .. 112480
  float* validf  = w + 112480;                          // .. 112780
  float* pooled  = w + 112780;                          // .. 259780
  float* feat    = w + 259780;                          // .. 874180 (16B aligned)
  float* db2     = w + 874180;                          // .. 877780 (16B aligned)
  float* msc2    = w + 877780;                          // .. 878680 (~3.5 MB total)

  hipMemsetAsync(hist, 0, 16385 * sizeof(unsigned int), stream);  // hist + cnt
  k_decode<<<68, 256, 0, stream>>>(cls, pred, boxes, scores, hist);
  k_compact<<<68, 256, 0, stream>>>(scores, hist, cnt, keys);
  k_nms1<<<1, 1024, 0, stream>>>(boxes, cnt, keys, out, rois_xy, validf);
  k_psroi<<<300, 256, 0, stream>>>(ft, rois_xy, pooled);
  k_fc1<<<dim3(8, 19), 256, 0, stream>>>(pooled, Wi, bi, feat);
  k_fc2<<<300, 256, 0, stream>>>(feat, Wc, bc, Wb, bb, rois_xy, validf, db2, msc2);
  k_nms2<<<1, 1024, 0, stream>>>(db2, msc2, out);
}

// Round 4
// 300.736 us; speedup vs baseline: 2.9482x; 1.0275x over previous
//
#include <hip/hip_runtime.h>

#define NB 17340      // 15*34*34
#define TOPK1 3000
#define TOPK2 300

__constant__ float c_AW[15] = {9.232984, 16.0, 27.712813, 18.465969, 32.0, 55.425626,
                               36.931937, 64.0, 110.851252, 73.863875, 128.0, 221.702503,
                               147.72775, 256.0, 443.405007};
__constant__ float c_AH[15] = {27.72668, 16.0, 9.237604, 55.453359, 32.0, 18.475209,
                               110.906719, 64.0, 36.950417, 221.813438, 128.0, 73.900834,
                               443.626876, 256.0, 147.801669};

__device__ __forceinline__ unsigned mapf(float f) {
  unsigned u = __float_as_uint(f);
  return (u & 0x80000000u) ? ~u : (u | 0x80000000u);
}
__device__ __forceinline__ float unmapf(unsigned m) {
  unsigned u = (m & 0x80000000u) ? (m & 0x7FFFFFFFu) : ~m;
  return __uint_as_float(u);
}
__device__ __forceinline__ float clipc(float v) {
  return fminf(fmaxf(v, 0.0f), 269.0f);
}

// ---------------- Kernel 1: RPN decode + keep filter + global histogram ----------------
__global__ void k_decode(const float* __restrict__ cls, const float* __restrict__ pred,
                         float* __restrict__ boxes, float* __restrict__ scores,
                         unsigned int* __restrict__ hist) {
  int i = blockIdx.x * 256 + threadIdx.x;
  if (i >= NB) return;
  int a = i / 1156;
  int rem = i - a * 1156;
  int y = rem / 34;
  int x = rem - y * 34;
  float fg = cls[(15 + a) * 1156 + rem];
  const float* p = pred + a * 4 * 1156 + rem;
  float t0 = p[0]    * (float)0.12677  + (float)0.000437;
  float t1 = p[1156] * (float)0.095741 + (float)0.002586;
  float t2 = p[2312] * (float)0.3173   + (float)-0.123953;
  float t3 = p[3468] * (float)0.281042 + (float)-0.081469;
  float aw = c_AW[a], ah = c_AH[a];
  float cx = t0 * aw + (float)x * 8.0f;
  float cy = t1 * ah + (float)y * 8.0f;
  float bw = expf(t2) * aw;
  float bh = expf(t3) * ah;
  float x1 = clipc(cx - 0.5f * (bw - 1.0f));
  float y1 = clipc(cy - 0.5f * (bh - 1.0f));
  float x2 = clipc(cx + 0.5f * (bw - 1.0f));
  float y2 = clipc(cy + 0.5f * (bh - 1.0f));
  boxes[i * 4 + 0] = x1;
  boxes[i * 4 + 1] = y1;
  boxes[i * 4 + 2] = x2;
  boxes[i * 4 + 3] = y2;
  float w2 = x2 - x1 + 1.0f, h2 = y2 - y1 + 1.0f;
  bool keep = (fg >= 0.2f) && ((w2 >= (float)6.16056) || (h2 >= (float)6.16056));
  scores[i] = keep ? fg : -1.0f;
  if (keep) atomicAdd(&hist[mapf(fg) >> 18], 1u);
}

// ---------------- Kernel 2: redundant cutoff + parallel compact ----------------
__global__ __launch_bounds__(256) void k_compact(const float* __restrict__ scores,
                                                 const unsigned int* __restrict__ hist,
                                                 unsigned int* __restrict__ cnt,
                                                 unsigned long long* __restrict__ keys) {
  const int t = threadIdx.x;
  __shared__ unsigned int sh[16384];
  __shared__ unsigned int coarse[256];
  __shared__ int s_B;
  for (int i = t; i < 16384; i += 256) sh[i] = hist[i];
  __syncthreads();
  {
    unsigned s = 0;
    int b0 = t * 64;
    for (int b = 0; b < 64; ++b) s += sh[b0 + b];
    coarse[t] = s;
  }
  __syncthreads();
  if (t == 0) {
    unsigned acc = 0, nbefore = 0;
    int C = 0;
    for (int c = 255; c >= 0; --c) {
      if (acc + coarse[c] >= (unsigned)TOPK1) { C = c; nbefore = acc; break; }
      acc += coarse[c];
    }
    unsigned acc2 = nbefore;
    int B = C * 64;
    for (int b = C * 64 + 63; b >= C * 64; --b) {
      if (acc2 + sh[b] >= (unsigned)TOPK1) { B = b; break; }
      acc2 += sh[b];
    }
    s_B = B;
  }
  __syncthreads();
  const unsigned B = (unsigned)s_B;
  int i = blockIdx.x * 256 + t;
  if (i < NB) {
    unsigned m = mapf(scores[i]);
    if ((m >> 18) >= B) {
      unsigned p = atomicAdd(cnt, 1u);
      if (p < 4096u) keys[p] = ((unsigned long long)m << 15) | (unsigned)(32767 - i);
    }
  }
}

// ---------------- Kernel 3: exact rank-by-count sort (64 blocks) ----------------
// keys unique -> rank(p) = #{q: key_q > key_p}; ranks < 3000 scatter (score, box).
__global__ __launch_bounds__(256) void k_sort(const float* __restrict__ boxes,
                                              const unsigned int* __restrict__ cnt,
                                              const unsigned long long* __restrict__ keys,
                                              unsigned int* __restrict__ sscore,
                                              float4* __restrict__ sbox) {
  const int t = threadIdx.x;
  __shared__ unsigned long long lk[4096];
  const int K = min((int)cnt[0], 4096);
  for (int i = t; i < K; i += 256) lk[i] = keys[i];
  __syncthreads();
  int p = blockIdx.x * 64 + (t >> 2);
  int s = t & 3;
  if (p < K) {
    unsigned long long kp = lk[p];
    int r = 0;
    for (int q = s; q < K; q += 4) r += (lk[q] > kp) ? 1 : 0;
    r += __shfl_xor(r, 1);
    r += __shfl_xor(r, 2);
    if (s == 0 && r < TOPK1) {
      int idx = 32767 - (int)(kp & 32767ull);
      sscore[r] = (unsigned)(kp >> 15);
      sbox[r] = ((const float4*)boxes)[idx];
    }
  }
}

// ---------------- Kernel 4: greedy NMS-300 from sorted arrays (LDS-resident) ----------------
__global__ __launch_bounds__(1024) void k_nms1(const unsigned int* __restrict__ cnt,
                                               const unsigned int* __restrict__ sscore,
                                               const float4* __restrict__ sbox,
                                               float* __restrict__ dout,
                                               float* __restrict__ rois_xy,
                                               float* __restrict__ validf) {
  const int t = threadIdx.x;
  __shared__ unsigned int sc[TOPK1];      // 12 KB
  __shared__ float4 bx_s[TOPK1];          // 48 KB
  __shared__ float4 abox[300];
  __shared__ float aar[300];
  __shared__ unsigned int ascm[300];
  __shared__ unsigned long long wsup[16];
  __shared__ int s_A;
  const int K3 = min((int)cnt[0], TOPK1);
  for (int i = t; i < TOPK1; i += 1024) {
    sc[i] = (i < K3) ? sscore[i] : 0u;
    bx_s[i] = (i < K3) ? sbox[i] : make_float4(0.f, 0.f, 0.f, 0.f);
  }
  if (t == 0) s_A = 0;
  __syncthreads();
  int A = 0;
  const int l = t & 63, w = t >> 6;
  for (int base = 0; base < TOPK1; base += 64) {
    if (A >= 300) break;
    if (sc[base] <= 0x80000000u) break;   // head score <= 0: nothing acceptable remains
    int rank = base + l;
    unsigned mk = (rank < TOPK1) ? sc[rank] : 0u;
    bool active = (mk > 0x80000000u);
    float4 bx = bx_s[rank < TOPK1 ? rank : 0];
    float area = (bx.z - bx.x + 1.0f) * (bx.w - bx.y + 1.0f);
    bool mysup = false;
    if (active) {
      for (int a = w; a < A; a += 16) {
        float4 ab = abox[a];
        float iw = fmaxf(fminf(bx.z, ab.z) - fmaxf(bx.x, ab.x) + 1.0f, 0.0f);
        float ih = fmaxf(fminf(bx.w, ab.w) - fmaxf(bx.y, ab.y) + 1.0f, 0.0f);
        float inter = iw * ih;
        float iou = inter / (area + aar[a] - inter);
        if (iou > 0.7f) { mysup = true; break; }
      }
    }
    unsigned long long bal0 = __ballot(mysup);
    if (l == 0) wsup[w] = bal0;
    __syncthreads();
    if (t < 64) {   // wave 0: in-chunk serial greedy
      unsigned long long supm = 0ull;
#pragma unroll
      for (int i = 0; i < 16; ++i) supm |= wsup[i];
      bool alive = active && !((supm >> l) & 1ull);
      unsigned long long bal = __ballot(alive);
      while (bal != 0ull && A < 300) {
        int j = __ffsll((unsigned long long)bal) - 1;  // lowest lane = highest key
        float jx1 = __shfl(bx.x, j), jy1 = __shfl(bx.y, j);
        float jx2 = __shfl(bx.z, j), jy2 = __shfl(bx.w, j);
        float jar = __shfl(area, j);
        if (l == j) { abox[A] = bx; aar[A] = area; ascm[A] = mk; }
        if (alive) {
          float iw = fmaxf(fminf(bx.z, jx2) - fmaxf(bx.x, jx1) + 1.0f, 0.0f);
          float ih = fmaxf(fminf(bx.w, jy2) - fmaxf(bx.y, jy1) + 1.0f, 0.0f);
          float inter = iw * ih;
          float iou = inter / (area + jar - inter);
          if (iou > 0.7f || l == j) alive = false;  // winner self-kills
        }
        A++;
        bal = __ballot(alive);
      }
      if (l == 0) s_A = A;
    }
    __syncthreads();
    A = s_A;
  }
  // parallel write-back of accepted results
  for (int a = t; a < A; a += 1024) {
    float4 b = abox[a];
    dout[30 + a * 5 + 0] = 0.0f;
    dout[30 + a * 5 + 1] = b.x;
    dout[30 + a * 5 + 2] = b.y;
    dout[30 + a * 5 + 3] = b.z;
    dout[30 + a * 5 + 4] = b.w;
    dout[1530 + a] = unmapf(ascm[a]);
    rois_xy[a * 4 + 0] = b.x; rois_xy[a * 4 + 1] = b.y;
    rois_xy[a * 4 + 2] = b.z; rois_xy[a * 4 + 3] = b.w;
    validf[a] = 1.0f;
  }
  for (int z = 30 + A * 5 + t; z < 1530; z += 1024) dout[z] = 0.f;
  for (int z = 1530 + A + t; z < 1830; z += 1024) dout[z] = 0.f;
  for (int z = A * 4 + t; z < 1200; z += 1024) rois_xy[z] = 0.f;
  for (int z = A + t; z < 300; z += 1024) validf[z] = 0.f;
}

// ---------------- Kernel 5: PSROI pooling (block per ROI) ----------------
__global__ __launch_bounds__(256) void k_psroi(const float* __restrict__ ft,
                                               const float* __restrict__ rois_xy,
                                               float* __restrict__ pooled) {
  int r = blockIdx.x;
  float r0 = rois_xy[r * 4 + 0], r1 = rois_xy[r * 4 + 1];
  float r2 = rois_xy[r * 4 + 2], r3 = rois_xy[r * 4 + 3];
  float sw = r0 * 0.125f;
  float sh = r1 * 0.125f;
  float ew = (r2 + 1.0f) * 0.125f;
  float eh = (r3 + 1.0f) * 0.125f;
  float rh = fmaxf(eh - sh, 0.1f);
  float rw = fmaxf(ew - sw, 0.1f);
  float bh = rh / 7.0f;
  float bwd = rw / 7.0f;
  for (int o = threadIdx.x; o < 490; o += 256) {
    int p = (o % 49) / 7;
    int q = o % 7;
    const float* base = ft + o * 1156;
    float acc = 0.f;
#pragma unroll
    for (int sy = 0; sy < 4; ++sy) {
      float ys = sh + (float)p * bh + ((float)sy + 0.5f) * (bh * 0.25f);
      float y0f = floorf(ys);
      float dy = ys - y0f;
      int y0 = (int)y0f;
      float wy0 = (1.0f - dy) * ((y0 >= 0 && y0 < 34) ? 1.f : 0.f);
      float wy1 = dy * ((y0 + 1 >= 0 && y0 + 1 < 34) ? 1.f : 0.f);
      int yc0 = min(max(y0, 0), 33), yc1 = min(max(y0 + 1, 0), 33);
#pragma unroll
      for (int sx = 0; sx < 4; ++sx) {
        float xs = sw + (float)q * bwd + ((float)sx + 0.5f) * (bwd * 0.25f);
        float x0f = floorf(xs);
        float dx = xs - x0f;
        int x0 = (int)x0f;
        float wx0 = (1.0f - dx) * ((x0 >= 0 && x0 < 34) ? 1.f : 0.f);
        float wx1 = dx * ((x0 + 1 >= 0 && x0 + 1 < 34) ? 1.f : 0.f);
        int xc0 = min(max(x0, 0), 33), xc1 = min(max(x0 + 1, 0), 33);
        float v00 = base[yc0 * 34 + xc0], v01 = base[yc0 * 34 + xc1];
        float v10 = base[yc1 * 34 + xc0], v11 = base[yc1 * 34 + xc1];
        acc += wy0 * wx0 * v00 + wy0 * wx1 * v01 + wy1 * wx0 * v10 + wy1 * wx1 * v11;
      }
    }
    pooled[r * 490 + o] = acc * (1.0f / 16.0f);
  }
}

// ---------------- Kernel 6: FC1 (490 -> 2048) + ReLU ----------------
__global__ __launch_bounds__(256) void k_fc1(const float* __restrict__ pooled,
                                             const float* __restrict__ Wi,
                                             const float* __restrict__ bi,
                                             float* __restrict__ feat) {
  __shared__ float pt[490][20];
  int t = threadIdx.x;
  int o = blockIdx.x * 256 + t;
  int r0 = blockIdx.y * 16;
  for (int idx = t; idx < 16 * 490; idx += 256) {
    int rr = idx / 490, kk = idx - rr * 490;
    pt[kk][rr] = (r0 + rr < 300) ? pooled[(r0 + rr) * 490 + kk] : 0.f;
  }
  __syncthreads();
  float acc[16];
#pragma unroll
  for (int e = 0; e < 16; ++e) acc[e] = 0.f;
  const float2* wrow2 = (const float2*)(Wi + o * 490);
  for (int k2 = 0; k2 < 245; ++k2) {
    float2 wv = wrow2[k2];
    int k = k2 * 2;
    const float4* p4a = (const float4*)(&pt[k][0]);
    const float4* p4b = (const float4*)(&pt[k + 1][0]);
    float4 a0 = p4a[0], a1 = p4a[1], a2 = p4a[2], a3 = p4a[3];
    float4 b0 = p4b[0], b1 = p4b[1], b2 = p4b[2], b3 = p4b[3];
    acc[0] += wv.x * a0.x + wv.y * b0.x;  acc[1] += wv.x * a0.y + wv.y * b0.y;
    acc[2] += wv.x * a0.z + wv.y * b0.z;  acc[3] += wv.x * a0.w + wv.y * b0.w;
    acc[4] += wv.x * a1.x + wv.y * b1.x;  acc[5] += wv.x * a1.y + wv.y * b1.y;
    acc[6] += wv.x * a1.z + wv.y * b1.z;  acc[7] += wv.x * a1.w + wv.y * b1.w;
    acc[8] += wv.x * a2.x + wv.y * b2.x;  acc[9] += wv.x * a2.y + wv.y * b2.y;
    acc[10] += wv.x * a2.z + wv.y * b2.z; acc[11] += wv.x * a2.w + wv.y * b2.w;
    acc[12] += wv.x * a3.x + wv.y * b3.x; acc[13] += wv.x * a3.y + wv.y * b3.y;
    acc[14] += wv.x * a3.z + wv.y * b3.z; acc[15] += wv.x * a3.w + wv.y * b3.w;
  }
  float bias = bi[o];
#pragma unroll
  for (int e = 0; e < 16; ++e) {
    int rr = r0 + e;
    if (rr < 300) feat[rr * 2048 + o] = fmaxf(acc[e] + bias, 0.f);
  }
}

// ---------------- Kernel 7: FC2 heads + softmax + per-class decode (fused) ----------------
__global__ __launch_bounds__(256) void k_fc2(const float* __restrict__ feat,
                                             const float* __restrict__ Wc,
                                             const float* __restrict__ bc,
                                             const float* __restrict__ Wb,
                                             const float* __restrict__ bb,
                                             const float* __restrict__ rois_xy,
                                             const float* __restrict__ validf,
                                             float* __restrict__ db2,
                                             float* __restrict__ msc2) {
  int r = blockIdx.x;
  int t = threadIdx.x;
  int l = t & 63, w = t >> 6;
  __shared__ float frow[2048];
  __shared__ float s_logit[20];
  __shared__ float s_probs[4];
  for (int i = t; i < 512; i += 256)
    ((float4*)frow)[i] = ((const float4*)(feat + r * 2048))[i];
  __syncthreads();
  for (int o = w; o < 20; o += 4) {
    const float* wr = (o < 4) ? (Wc + o * 2048) : (Wb + (o - 4) * 2048);
    float p = 0.f;
#pragma unroll
    for (int j = 0; j < 8; ++j) {
      float4 wv = ((const float4*)wr)[l + 64 * j];
      float4 fv = ((const float4*)frow)[l + 64 * j];
      p += wv.x * fv.x + wv.y * fv.y + wv.z * fv.z + wv.w * fv.w;
    }
    for (int off = 32; off > 0; off >>= 1) p += __shfl_xor(p, off);
    if (l == 0) s_logit[o] = p + ((o < 4) ? bc[o] : bb[o - 4]);
  }
  __syncthreads();
  if (t == 0) {
    float m = fmaxf(fmaxf(s_logit[0], s_logit[1]), fmaxf(s_logit[2], s_logit[3]));
    float e0 = expf(s_logit[0] - m), e1 = expf(s_logit[1] - m);
    float e2 = expf(s_logit[2] - m), e3 = expf(s_logit[3] - m);
    float ssum = e0 + e1 + e2 + e3;
    s_probs[0] = e0 / ssum; s_probs[1] = e1 / ssum;
    s_probs[2] = e2 / ssum; s_probs[3] = e3 / ssum;
  }
  __syncthreads();
  if (t < 3) {
    int c = t + 1;
    float x1 = rois_xy[r * 4 + 0], y1 = rois_xy[r * 4 + 1];
    float x2 = rois_xy[r * 4 + 2], y2 = rois_xy[r * 4 + 3];
    float rwv = x2 - x1 + 1.0f, rhv = y2 - y1 + 1.0f;
    float rcx = x1 + 0.5f * (rwv - 1.0f), rcy = y1 + 0.5f * (rhv - 1.0f);
    float t0 = s_logit[4 + 4 * c + 0] * 0.1f;
    float t1 = s_logit[4 + 4 * c + 1] * 0.1f;
    float t2 = s_logit[4 + 4 * c + 2] * 0.2f;
    float t3 = s_logit[4 + 4 * c + 3] * 0.2f;
    float cx = t0 * rwv + rcx, cy = t1 * rhv + rcy;
    float bw = expf(t2) * rwv, bh = expf(t3) * rhv;
    float dx1 = clipc(cx - 0.5f * (bw - 1.0f));
    float dy1 = clipc(cy - 0.5f * (bh - 1.0f));
    float dx2 = clipc(cx + 0.5f * (bw - 1.0f));
    float dy2 = clipc(cy + 0.5f * (bh - 1.0f));
    float dw = dx2 - dx1 + 1.0f, dh = dy2 - dy1 + 1.0f;
    float sc = s_probs[c];
    bool objok = (1.0f - s_probs[0]) >= 0.1f;
    bool valid = validf[r] > 0.5f;
    bool kf = valid && objok && (sc >= 0.1f) && ((dw >= (float)8.8008) || (dh >= (float)8.8008));
    int i2 = (c - 1) * 300 + r;
    db2[i2 * 4 + 0] = dx1; db2[i2 * 4 + 1] = dy1;
    db2[i2 * 4 + 2] = dx2; db2[i2 * 4 + 3] = dy2;
    msc2[i2] = kf ? sc : -1.0f;
  }
}

// ---------------- Kernel 8: rank-sort 900 + greedy NMS-5 -> bboxes ----------------
__global__ __launch_bounds__(1024) void k_nms2(const float* __restrict__ db2,
                                               const float* __restrict__ msc2,
                                               float* __restrict__ dout) {
  const int t = threadIdx.x;
  __shared__ unsigned long long lk[900];
  __shared__ unsigned long long sk[1024];
  __shared__ float4 abox[5];
  __shared__ float aar[5];
  __shared__ int s_A;
  sk[t] = 0ull;
  if (t < 900) lk[t] = ((unsigned long long)mapf(msc2[t]) << 10) | (unsigned)(1023 - t);
  if (t == 0) s_A = 0;
  __syncthreads();
  if (t < 900) {
    unsigned long long kp = lk[t];
    int r = 0;
    for (int q = 0; q < 900; ++q) r += (lk[q] > kp) ? 1 : 0;
    sk[r] = kp;   // keys unique -> ranks unique
  }
  __syncthreads();
  if (t < 64) {
    int A = 0;
    for (int base = 0; base < TOPK2 && A < 5; base += 64) {
      unsigned headm = (unsigned)(sk[base] >> 10);
      if (headm <= 0x80000000u) break;
      int rank = base + t;
      unsigned long long key = sk[rank];
      unsigned mk = (unsigned)(key >> 10);
      bool active = (rank < TOPK2) && (mk > 0x80000000u);
      int idx = 1023 - (int)(key & 1023ull);
      float4 bx = make_float4(0.f, 0.f, 0.f, 0.f);
      float area = 0.f;
      if (active) {
        bx = ((const float4*)db2)[idx];
        area = (bx.z - bx.x + 1.0f) * (bx.w - bx.y + 1.0f);
      }
      bool alive = active;
      for (int a = 0; a < A; ++a) {
        float4 ab = abox[a];
        float iw = fmaxf(fminf(bx.z, ab.z) - fmaxf(bx.x, ab.x) + 1.0f, 0.0f);
        float ih = fmaxf(fminf(bx.w, ab.w) - fmaxf(bx.y, ab.y) + 1.0f, 0.0f);
        float inter = iw * ih;
        float iou = inter / (area + aar[a] - inter);
        if (iou > 0.5f) { alive = false; break; }
      }
      unsigned long long bal = __ballot(alive);
      while (bal != 0ull && A < 5) {
        int j = __ffsll((unsigned long long)bal) - 1;
        float jx1 = __shfl(bx.x, j), jy1 = __shfl(bx.y, j);
        float jx2 = __shfl(bx.z, j), jy2 = __shfl(bx.w, j);
        float jar = __shfl(area, j);
        if (t == j) {
          abox[A] = bx; aar[A] = area;
          dout[A * 6 + 0] = bx.x; dout[A * 6 + 1] = bx.y;
          dout[A * 6 + 2] = bx.z; dout[A * 6 + 3] = bx.w;
          dout[A * 6 + 4] = unmapf(mk);
          dout[A * 6 + 5] = (float)(idx / 300 + 1);
        }
        if (alive) {
          float iw = fmaxf(fminf(bx.z, jx2) - fmaxf(bx.x, jx1) + 1.0f, 0.0f);
          float ih = fmaxf(fminf(bx.w, jy2) - fmaxf(bx.y, jy1) + 1.0f, 0.0f);
          float inter = iw * ih;
          float iou = inter / (area + jar - inter);
          if (iou > 0.5f || t == j) alive = false;
        }
        A++;
        bal = __ballot(alive);
      }
    }
    if (t == 0) s_A = A;
  }
  __syncthreads();
  int A = s_A;
  for (int z = A * 6 + t; z < 30; z += 1024) dout[z] = 0.f;
}

extern "C" void kernel_launch(void* const* d_in, const int* in_sizes, int n_in,
                              void* d_out, int out_size, void* d_ws, size_t ws_size,
                              hipStream_t stream) {
  const float* cls  = (const float*)d_in[0];
  const float* pred = (const float*)d_in[1];
  const float* ft   = (const float*)d_in[2];
  const float* Wi   = (const float*)d_in[3];
  const float* bi   = (const float*)d_in[4];
  const float* Wc   = (const float*)d_in[5];
  const float* bc   = (const float*)d_in[6];
  const float* Wb   = (const float*)d_in[7];
  const float* bb   = (const float*)d_in[8];
  float* out = (float*)d_out;
  float* w = (float*)d_ws;
  // layout (float offsets)
  float* boxes   = w;                                   // 0      .. 69360
  float* scores  = w + 69360;                           // 69360  .. 86700
  unsigned int* hist = (unsigned int*)(w + 86700);      // 86700  .. 103084
  unsigned int* cnt  = (unsigned int*)(w + 103084);     // 103084 .. 103085 (pad to 103088)
  unsigned long long* keys = (unsigned long long*)(w + 103088); // 4096 u64 -> 111280
  unsigned int* sscore = (unsigned int*)(w + 111280);   // 3000 u32 -> 114280
  float4* sbox   = (float4*)(w + 114280);               // 3000 f4 (16B aligned) -> 126280
  float* rois_xy = w + 126280;                          // .. 127480
  float* validf  = w + 127480;                          // .. 127780
  float* pooled  = w + 127780;                          // .. 274780
  float* feat    = w + 274780;                          // .. 889180 (16B aligned)
  float* db2     = w + 889180;                          // .. 892780 (16B aligned)
  float* msc2    = w + 892780;                          // .. 893680 (~3.57 MB)

  hipMemsetAsync(hist, 0, 16385 * sizeof(unsigned int), stream);  // hist + cnt
  k_decode<<<68, 256, 0, stream>>>(cls, pred, boxes, scores, hist);
  k_compact<<<68, 256, 0, stream>>>(scores, hist, cnt, keys);
  k_sort<<<64, 256, 0, stream>>>(boxes, cnt, keys, sscore, sbox);
  k_nms1<<<1, 1024, 0, stream>>>(cnt, sscore, sbox, out, rois_xy, validf);
  k_psroi<<<300, 256, 0, stream>>>(ft, rois_xy, pooled);
  k_fc1<<<dim3(8, 19), 256, 0, stream>>>(pooled, Wi, bi, feat);
  k_fc2<<<300, 256, 0, stream>>>(feat, Wc, bc, Wb, bb, rois_xy, validf, db2, msc2);
  k_nms2<<<1, 1024, 0, stream>>>(db2, msc2, out);
}